// Round 8
// baseline (713.476 us; speedup 1.0000x reference)
//
#include <hip/hip_runtime.h>
#include <hip/hip_bf16.h>

#define R_ 3
#define N_ 20000
#define NP_ 20096          // padded rows per relation (157 * 128)
#define E_ 250000
#define H_ 4
#define D_ 32
#define IN_ 128
#define NEG_ 0.2f

static __device__ __forceinline__ float leaky(float v) { return v >= 0.f ? v : NEG_ * v; }

static __device__ __forceinline__ float red32(float v) {
    #pragma unroll
    for (int m = 16; m > 0; m >>= 1) v += __shfl_xor(v, m, 64);
    return v;
}

// ---------------- CSR build ----------------
__global__ void count_kernel(const int* __restrict__ dst, int* __restrict__ cnt) {
    int i = blockIdx.x * blockDim.x + threadIdx.x;
    if (i < R_ * E_) {
        int r = i / E_;
        atomicAdd(&cnt[r * N_ + dst[i]], 1);
    }
}

__global__ __launch_bounds__(1024)
void scan_kernel(const int* __restrict__ cnt, int* __restrict__ rowptr, int* __restrict__ cursor) {
    const int r = blockIdx.x;
    const int t = threadIdx.x;
    const int CH = 20;               // 1024*20 >= 20000
    int local[CH];
    int s = 0;
    int b0 = t * CH;
    #pragma unroll
    for (int i = 0; i < CH; i++) {
        int idx = b0 + i;
        int v = (idx < N_) ? cnt[r * N_ + idx] : 0;
        local[i] = s;                // exclusive within thread
        s += v;
    }
    __shared__ int ts[1024];
    ts[t] = s;
    __syncthreads();
    for (int off = 1; off < 1024; off <<= 1) {
        int v = (t >= off) ? ts[t - off] : 0;
        __syncthreads();
        ts[t] += v;
        __syncthreads();
    }
    int texcl = ts[t] - s;
    #pragma unroll
    for (int i = 0; i < CH; i++) {
        int idx = b0 + i;
        if (idx < N_) {
            int p = texcl + local[i];
            rowptr[r * (N_ + 1) + idx] = p;
            cursor[r * N_ + idx] = p;
        }
    }
    if (t == 1023) rowptr[r * (N_ + 1) + N_] = ts[1023];
}

__global__ void fill_kernel(const int* __restrict__ src, const int* __restrict__ dst,
                            int* __restrict__ cursor, int* __restrict__ csr,
                            int* __restrict__ posmap) {
    int i = blockIdx.x * blockDim.x + threadIdx.x;
    if (i < R_ * E_) {
        int r = i / E_;
        int d = dst[i];
        int pos = atomicAdd(&cursor[r * N_ + d], 1);   // relation-local slot
        csr[r * E_ + pos] = src[i];
        posmap[i] = pos;
    }
}

// ---------------- tiny relation-embedding kernels ----------------
__global__ void ra_kernel(const float* __restrict__ re, const float* __restrict__ Wr,
                          float* __restrict__ ra, int relin) {
    int r = blockIdx.x, c = threadIdx.x;  // 256 threads
    float a = 0.f;
    for (int i = 0; i < relin; i++) a += re[r * relin + i] * Wr[(r * relin + i) * 256 + c];
    ra[r * 256 + c] = a;
}

__global__ void prop_kernel(const float* __restrict__ re, const float* __restrict__ Wp,
                            const float* __restrict__ bp, float* __restrict__ out, int relin) {
    int r = blockIdx.x, o = threadIdx.x;  // 128
    float a = bp[r * 128 + o];
    for (int i = 0; i < relin; i++) a += re[r * relin + i] * Wp[(r * relin + i) * 128 + o];
    out[r * 128 + o] = a;
}

__global__ void rp_kernel(const float* __restrict__ re2, const float* __restrict__ Wrf,
                          float* __restrict__ rp) {
    int r = blockIdx.x, t = threadIdx.x, h = t >> 5, d = t & 31;
    float a = 0.f;
    #pragma unroll
    for (int c = 0; c < 32; c++)
        a += re2[r * 128 + h * 32 + c] * Wrf[(((r * H_ + h) * D_) + c) * D_ + d];
    rp[r * 128 + t] = a;
}

// ---------------- register-tiled GEMM (projection): 128x128 tile, 8x8/thread ----------------
__global__ __launch_bounds__(256)
void gemm_tile(const float* __restrict__ X, int ldrows, int nrows,
               const float* __restrict__ W, const float* __restrict__ bias,
               float* __restrict__ Y) {
    const int t  = threadIdx.x;
    const int tx = t & 15;
    const int ty = t >> 4;
    const int r  = blockIdx.y;
    const int row0 = blockIdx.x * 128;

    const float* Xrel = X + (size_t)r * ldrows * 128;
    float*       Yrel = Y + (size_t)r * NP_ * 128;

    __shared__ float As[32][132];     // transposed, padded (+4) vs bank conflicts
    __shared__ float Bs[32][128];

    float acc[8][8];
    #pragma unroll
    for (int i = 0; i < 8; i++)
        #pragma unroll
        for (int j = 0; j < 8; j++) acc[i][j] = 0.f;

    const int kq = t & 7;
    for (int kb = 0; kb < 128; kb += 32) {
        __syncthreads();
        #pragma unroll
        for (int j = 0; j < 4; j++) {
            int rowl = (t >> 3) + 32 * j;
            int rowg = row0 + rowl;
            int rowc = rowg < nrows ? rowg : nrows - 1;
            float4 v = *(const float4*)&Xrel[(size_t)rowc * 128 + kb + kq * 4];
            As[kq * 4 + 0][rowl] = v.x;
            As[kq * 4 + 1][rowl] = v.y;
            As[kq * 4 + 2][rowl] = v.z;
            As[kq * 4 + 3][rowl] = v.w;
        }
        #pragma unroll
        for (int j = 0; j < 4; j++) {
            int fi = t + 256 * j;
            int kk = fi >> 5;
            int colq = fi & 31;
            *(float4*)&Bs[kk][colq * 4] = *(const float4*)&W[(size_t)(kb + kk) * 128 + colq * 4];
        }
        __syncthreads();
        #pragma unroll 8
        for (int k = 0; k < 32; k++) {
            float a[8], b[8];
            *(float4*)&a[0] = *(const float4*)&As[k][ty * 8];
            *(float4*)&a[4] = *(const float4*)&As[k][ty * 8 + 4];
            *(float4*)&b[0] = *(const float4*)&Bs[k][tx * 8];
            *(float4*)&b[4] = *(const float4*)&Bs[k][tx * 8 + 4];
            #pragma unroll
            for (int i = 0; i < 8; i++)
                #pragma unroll
                for (int j = 0; j < 8; j++) acc[i][j] += a[i] * b[j];
        }
    }

    const int col0 = tx * 8;
    float bq[8];
    #pragma unroll
    for (int j = 0; j < 8; j++) bq[j] = bias ? bias[col0 + j] : 0.f;
    #pragma unroll
    for (int i = 0; i < 8; i++) {
        int row = row0 + ty * 8 + i;
        float4 o0 = {acc[i][0] + bq[0], acc[i][1] + bq[1], acc[i][2] + bq[2], acc[i][3] + bq[3]};
        float4 o1 = {acc[i][4] + bq[4], acc[i][5] + bq[5], acc[i][6] + bq[6], acc[i][7] + bq[7]};
        *(float4*)&Yrel[(size_t)row * 128 + col0]     = o0;
        *(float4*)&Yrel[(size_t)row * 128 + col0 + 4] = o1;
    }
}

// ---------------- fused dual GEMM: 128x256 tile (Wres | Wn), 512 threads ----------------
// Ya = X@Wa + ba (residual), Yb = X@Wb (messages) + attention dots from acc.
__global__ __launch_bounds__(512)
void gemm_dual(const float* __restrict__ X, int ldrows, int nrows,
               const float* __restrict__ Wa, const float* __restrict__ ba,
               float* __restrict__ Ya,
               const float* __restrict__ Wb, float* __restrict__ Yb,
               const float* __restrict__ ra, float* __restrict__ esrc,
               float* __restrict__ edst) {
    const int t  = threadIdx.x;
    const int tx = t & 31;            // 32 col groups of 8 (0-15 -> Wa, 16-31 -> Wb)
    const int ty = t >> 5;            // 16 row groups of 8
    const int r  = blockIdx.y;
    const int row0 = blockIdx.x * 128;

    const float* Xrel = X + (size_t)r * ldrows * 128;

    __shared__ float As[32][132];     // transposed, padded
    __shared__ float Bs[32][256];     // [k][col]: cols 0-127 Wa, 128-255 Wb

    float acc[8][8];
    #pragma unroll
    for (int i = 0; i < 8; i++)
        #pragma unroll
        for (int j = 0; j < 8; j++) acc[i][j] = 0.f;

    const int kq = t & 7;
    for (int kb = 0; kb < 128; kb += 32) {
        __syncthreads();
        // stage A: 128 rows x 32 k, transposed
        #pragma unroll
        for (int j = 0; j < 2; j++) {
            int rowl = (t >> 3) + 64 * j;
            int rowg = row0 + rowl;
            int rowc = rowg < nrows ? rowg : nrows - 1;
            float4 v = *(const float4*)&Xrel[(size_t)rowc * 128 + kb + kq * 4];
            As[kq * 4 + 0][rowl] = v.x;
            As[kq * 4 + 1][rowl] = v.y;
            As[kq * 4 + 2][rowl] = v.z;
            As[kq * 4 + 3][rowl] = v.w;
        }
        // stage B: 32 k x 256 cols (Wa | Wb)
        #pragma unroll
        for (int j = 0; j < 4; j++) {
            int fi = t + 512 * j;
            int kk = fi >> 6;
            int colq = fi & 63;
            float4 v = (colq < 32)
                ? *(const float4*)&Wa[(size_t)(kb + kk) * 128 + colq * 4]
                : *(const float4*)&Wb[(size_t)(kb + kk) * 128 + (colq - 32) * 4];
            *(float4*)&Bs[kk][colq * 4] = v;
        }
        __syncthreads();
        #pragma unroll 8
        for (int k = 0; k < 32; k++) {
            float a[8], b[8];
            *(float4*)&a[0] = *(const float4*)&As[k][ty * 8];
            *(float4*)&a[4] = *(const float4*)&As[k][ty * 8 + 4];
            *(float4*)&b[0] = *(const float4*)&Bs[k][tx * 8];
            *(float4*)&b[4] = *(const float4*)&Bs[k][tx * 8 + 4];
            #pragma unroll
            for (int i = 0; i < 8; i++)
                #pragma unroll
                for (int j = 0; j < 8; j++) acc[i][j] += a[i] * b[j];
        }
    }

    if (tx < 16) {                    // residual half
        const int col0 = tx * 8;
        float bq[8];
        #pragma unroll
        for (int j = 0; j < 8; j++) bq[j] = ba[col0 + j];
        float* Yrel = Ya + (size_t)r * NP_ * 128;
        #pragma unroll
        for (int i = 0; i < 8; i++) {
            int row = row0 + ty * 8 + i;
            float4 o0 = {acc[i][0] + bq[0], acc[i][1] + bq[1], acc[i][2] + bq[2], acc[i][3] + bq[3]};
            float4 o1 = {acc[i][4] + bq[4], acc[i][5] + bq[5], acc[i][6] + bq[6], acc[i][7] + bq[7]};
            *(float4*)&Yrel[(size_t)row * 128 + col0]     = o0;
            *(float4*)&Yrel[(size_t)row * 128 + col0 + 4] = o1;
        }
    } else {                          // message half + attention dots
        const int col0 = (tx - 16) * 8;
        float* Yrel = Yb + (size_t)r * NP_ * 128;
        #pragma unroll
        for (int i = 0; i < 8; i++) {
            int row = row0 + ty * 8 + i;
            float4 o0 = {acc[i][0], acc[i][1], acc[i][2], acc[i][3]};
            float4 o1 = {acc[i][4], acc[i][5], acc[i][6], acc[i][7]};
            *(float4*)&Yrel[(size_t)row * 128 + col0]     = o0;
            *(float4*)&Yrel[(size_t)row * 128 + col0 + 4] = o1;
        }
        const int hh = (tx - 16) >> 2;
        float rad[8], ras[8];
        #pragma unroll
        for (int j = 0; j < 8; j++) {
            int c = ((tx - 16) & 3) * 8 + j;
            rad[j] = ra[(r * H_ + hh) * 64 + c];
            ras[j] = ra[(r * H_ + hh) * 64 + 32 + c];
        }
        #pragma unroll
        for (int i = 0; i < 8; i++) {
            float vd = 0.f, vs = 0.f;
            #pragma unroll
            for (int j = 0; j < 8; j++) { vd += acc[i][j] * rad[j]; vs += acc[i][j] * ras[j]; }
            vd += __shfl_xor(vd, 1); vd += __shfl_xor(vd, 2);
            vs += __shfl_xor(vs, 1); vs += __shfl_xor(vs, 2);
            if (((tx - 16) & 3) == 0) {
                int row = row0 + ty * 8 + i;
                edst[((size_t)r * NP_ + row) * 4 + hh] = vd;
                esrc[((size_t)r * NP_ + row) * 4 + hh] = vs;
            }
        }
    }
}

// ---------------- edge-parallel attention numerator ----------------
__global__ void edgep_kernel(const int* __restrict__ src, const int* __restrict__ dst,
                             const int* __restrict__ posmap,
                             const float* __restrict__ esrc, const float* __restrict__ edst,
                             float4* __restrict__ pbuf) {
    int i = blockIdx.x * blockDim.x + threadIdx.x;
    if (i >= R_ * E_) return;
    int r = i / E_;
    int s = src[i], d = dst[i];
    const float4 es = *(const float4*)&esrc[((size_t)r * NP_ + s) * 4];
    const float4 ed = *(const float4*)&edst[((size_t)r * NP_ + d) * 4];
    float4 p;
    p.x = __expf(leaky(es.x + ed.x));
    p.y = __expf(leaky(es.y + ed.y));
    p.z = __expf(leaky(es.z + ed.z));
    p.w = __expf(leaky(es.w + ed.w));
    pbuf[(size_t)r * E_ + posmap[i]] = p;
}

// ---------------- fused: aggregate(+relu,+residual gate) -> cross attn [-> fusing] ----
// 384 threads: group g = relation; per group the round-5 aggregate layout.
// FUSE=false: write cross output to fout[r][NP][128]. FUSE=true: also apply
// RelationFusing (Wnf, rp) and write final out[n][128].
template <bool FUSE>
__global__ __launch_bounds__(384)
void agg_cross(const float* __restrict__ hbuf, const float* __restrict__ pbuf,
               const int* __restrict__ rowptr, const int* __restrict__ csr,
               const float* __restrict__ resw, const float* __restrict__ res,
               const float* __restrict__ Wx, float* __restrict__ fout,
               const float* __restrict__ Wnf, const float* __restrict__ rp,
               float* __restrict__ out) {
    const int n = blockIdx.x;
    const int t = threadIdx.x;
    const int g = t >> 7;             // relation
    const int tl = t & 127;
    const int lane32 = tl & 31;       // channel quad
    const int slot = tl >> 5;         // edge slot
    const int h = lane32 >> 3;

    const int beg = rowptr[g * (N_ + 1) + n];
    const int end = rowptr[g * (N_ + 1) + n + 1];

    float4 acc = {0.f, 0.f, 0.f, 0.f};
    float psum = 0.f;
    for (int j0 = beg; j0 < end; j0 += 4) {
        int j = j0 + slot;
        bool valid = j < end;
        int jc = valid ? j : beg;
        int s = csr[g * E_ + jc];
        float p = valid ? ((const float*)pbuf)[((size_t)g * E_ + j) * 4 + h] : 0.f;
        const float4 hv = *(const float4*)&hbuf[((size_t)g * NP_ + s) * 128 + lane32 * 4];
        acc.x += p * hv.x; acc.y += p * hv.y; acc.z += p * hv.z; acc.w += p * hv.w;
        psum += p;
    }

    __shared__ float4 sacc[3][4][32];
    __shared__ float spsum[3][4][32];
    __shared__ float sf[3][128];
    sacc[g][slot][lane32] = acc;
    spsum[g][slot][lane32] = psum;
    __syncthreads();
    if (tl < 32) {
        float4 a0 = sacc[g][0][tl], a1 = sacc[g][1][tl], a2 = sacc[g][2][tl], a3 = sacc[g][3][tl];
        float ps = spsum[g][0][tl] + spsum[g][1][tl] + spsum[g][2][tl] + spsum[g][3][tl];
        float inv = 1.f / (ps + 1e-16f);
        float alpha = 1.f / (1.f + __expf(-resw[0]));
        const float4 rs = *(const float4*)&res[((size_t)g * NP_ + n) * 128 + tl * 4];
        float4 o;
        o.x = fmaxf((a0.x + a1.x + a2.x + a3.x) * inv, 0.f) * alpha + rs.x * (1.f - alpha);
        o.y = fmaxf((a0.y + a1.y + a2.y + a3.y) * inv, 0.f) * alpha + rs.y * (1.f - alpha);
        o.z = fmaxf((a0.z + a1.z + a2.z + a3.z) * inv, 0.f) * alpha + rs.z * (1.f - alpha);
        o.w = fmaxf((a0.w + a1.w + a2.w + a3.w) * inv, 0.f) * alpha + rs.w * (1.f - alpha);
        *(float4*)&sf[g][tl * 4] = o;
    }
    __syncthreads();

    float fc0 = 0.f, fc1 = 0.f, fc2 = 0.f;
    if (t < 128) {
        float f0 = sf[0][t], f1 = sf[1][t], f2 = sf[2][t];
        #pragma unroll
        for (int k = 0; k < 3; k++) {
            float w = Wx[k * 128 + t];
            float s0 = leaky(red32(f0 * w));
            float s1 = leaky(red32(f1 * w));
            float s2 = leaky(red32(f2 * w));
            float mx = fmaxf(s0, fmaxf(s1, s2));
            float a0 = __expf(s0 - mx), a1 = __expf(s1 - mx), a2 = __expf(s2 - mx);
            float den = a0 + a1 + a2;
            float v = (f0 * a0 + f1 * a1 + f2 * a2) / den;
            if (k == 0) fc0 = v; else if (k == 1) fc1 = v; else fc2 = v;
            if (!FUSE) fout[((size_t)k * NP_ + n) * 128 + t] = v;
        }
    }
    if (FUSE) {
        __syncthreads();
        if (t < 128) { sf[0][t] = fc0; sf[1][t] = fc1; sf[2][t] = fc2; }
        __syncthreads();
        if (t < 128) {
            const int hh = t >> 5, e = t & 31;
            float hf[3];
            #pragma unroll
            for (int r = 0; r < 3; r++) {
                float a = 0.f;
                #pragma unroll
                for (int d = 0; d < 32; d++)
                    a += sf[r][hh * 32 + d] * Wnf[(((r * H_ + hh) * D_) + d) * D_ + e];
                hf[r] = a;
            }
            float s0 = leaky(red32(hf[0] * rp[0 * 128 + t]));
            float s1 = leaky(red32(hf[1] * rp[1 * 128 + t]));
            float s2 = leaky(red32(hf[2] * rp[2 * 128 + t]));
            float mx = fmaxf(s0, fmaxf(s1, s2));
            float a0 = __expf(s0 - mx), a1 = __expf(s1 - mx), a2 = __expf(s2 - mx);
            float den = a0 + a1 + a2;
            out[(size_t)n * 128 + t] = (hf[0] * a0 + hf[1] * a1 + hf[2] * a2) / den;
        }
    }
}

extern "C" void kernel_launch(void* const* d_in, const int* in_sizes, int n_in,
                              void* d_out, int out_size, void* d_ws, size_t ws_size,
                              hipStream_t stream) {
    const float* x        = (const float*)d_in[0];
    const int*   src      = (const int*)d_in[1];
    const int*   dst      = (const int*)d_in[2];
    const float* proj_W   = (const float*)d_in[3];
    const float* proj_b   = (const float*)d_in[4];
    const float* rel_emb0 = (const float*)d_in[5];
    const float* Wn0      = (const float*)d_in[6];
    const float* Wr0      = (const float*)d_in[7];
    const float* Wp0      = (const float*)d_in[8];
    const float* bp0      = (const float*)d_in[9];
    const float* Wres0    = (const float*)d_in[10];
    const float* bres0    = (const float*)d_in[11];
    const float* resw0    = (const float*)d_in[12];
    const float* Wx0      = (const float*)d_in[13];
    const float* Wn1      = (const float*)d_in[14];
    const float* Wr1      = (const float*)d_in[15];
    const float* Wp1      = (const float*)d_in[16];
    const float* bp1      = (const float*)d_in[17];
    const float* Wres1    = (const float*)d_in[18];
    const float* bres1    = (const float*)d_in[19];
    const float* resw1    = (const float*)d_in[20];
    const float* Wx1      = (const float*)d_in[21];
    const float* Wnf      = (const float*)d_in[22];
    const float* Wrf      = (const float*)d_in[23];

    char* ws = (char*)d_ws;
    size_t off = 0;
    auto alloc = [&](size_t bytes) { char* p = ws + off; off = (off + bytes + 255) & ~(size_t)255; return p; };
    const size_t BIG = (size_t)R_ * NP_ * 128 * sizeof(float);
    float* xp    = (float*)alloc(BIG);
    float* bufA  = (float*)alloc(BIG);   // residual (X@Wres+b)
    float* bufB  = (float*)alloc(BIG);   // cross output / next-layer input
    float* hbuf  = (float*)alloc(BIG);   // messages (X@Wn)
    float* pbuf  = (float*)alloc((size_t)R_ * E_ * 4 * sizeof(float));
    int*   posmap= (int*)alloc((size_t)R_ * E_ * sizeof(int));
    float* esrc  = (float*)alloc((size_t)R_ * NP_ * H_ * sizeof(float));
    float* edst  = (float*)alloc((size_t)R_ * NP_ * H_ * sizeof(float));
    int*   cnt   = (int*)alloc((size_t)R_ * N_ * sizeof(int));
    int*   cursor= (int*)alloc((size_t)R_ * N_ * sizeof(int));
    int*   rowptr= (int*)alloc((size_t)R_ * (N_ + 1) * sizeof(int));
    int*   csr   = (int*)alloc((size_t)R_ * E_ * sizeof(int));
    float* remb1 = (float*)alloc((size_t)R_ * 128 * sizeof(float));
    float* remb2 = (float*)alloc((size_t)R_ * 128 * sizeof(float));
    float* ra0   = (float*)alloc((size_t)R_ * 256 * sizeof(float));
    float* ra1   = (float*)alloc((size_t)R_ * 256 * sizeof(float));
    float* rpb   = (float*)alloc((size_t)R_ * 128 * sizeof(float));

    // ---- CSR build (shared by both layers) ----
    hipMemsetAsync(cnt, 0, (size_t)R_ * N_ * sizeof(int), stream);
    const int EB = (R_ * E_ + 255) / 256;
    count_kernel<<<EB, 256, 0, stream>>>(dst, cnt);
    scan_kernel<<<R_, 1024, 0, stream>>>(cnt, rowptr, cursor);
    fill_kernel<<<EB, 256, 0, stream>>>(src, dst, cursor, csr, posmap);

    // ---- relation-embedding chain ----
    ra_kernel<<<R_, 256, 0, stream>>>(rel_emb0, Wr0, ra0, 64);
    prop_kernel<<<R_, 128, 0, stream>>>(rel_emb0, Wp0, bp0, remb1, 64);
    ra_kernel<<<R_, 256, 0, stream>>>(remb1, Wr1, ra1, 128);
    prop_kernel<<<R_, 128, 0, stream>>>(remb1, Wp1, bp1, remb2, 128);
    rp_kernel<<<R_, 128, 0, stream>>>(remb2, Wrf, rpb);

    const dim3 GT(NP_ / 128, R_);   // 157 x 3 tile blocks
    // ---- projection ----
    gemm_tile<<<GT, 256, 0, stream>>>(x, N_, N_, proj_W, proj_b, xp);
    // ---- layer 0 ----
    gemm_dual<<<GT, 512, 0, stream>>>(xp, NP_, NP_, Wres0, bres0, bufA,
                                      Wn0, hbuf, ra0, esrc, edst);
    edgep_kernel<<<EB, 256, 0, stream>>>(src, dst, posmap, esrc, edst, (float4*)pbuf);
    agg_cross<false><<<N_, 384, 0, stream>>>(hbuf, pbuf, rowptr, csr, resw0, bufA,
                                             Wx0, bufB, nullptr, nullptr, nullptr);
    // ---- layer 1 (cross + relation-fusing fused into epilogue) ----
    gemm_dual<<<GT, 512, 0, stream>>>(bufB, NP_, NP_, Wres1, bres1, bufA,
                                      Wn1, hbuf, ra1, esrc, edst);
    edgep_kernel<<<EB, 256, 0, stream>>>(src, dst, posmap, esrc, edst, (float4*)pbuf);
    agg_cross<true><<<N_, 384, 0, stream>>>(hbuf, pbuf, rowptr, csr, resw1, bufA,
                                            Wx1, nullptr, Wnf, rpb, (float*)d_out);
}

// Round 9
// 687.219 us; speedup vs baseline: 1.0382x; 1.0382x over previous
//
#include <hip/hip_runtime.h>
#include <hip/hip_bf16.h>

#define R_ 3
#define N_ 20000
#define NP_ 20096          // padded rows per relation (157 * 128)
#define E_ 250000
#define H_ 4
#define D_ 32
#define IN_ 128
#define NEG_ 0.2f

static __device__ __forceinline__ float leaky(float v) { return v >= 0.f ? v : NEG_ * v; }

static __device__ __forceinline__ float red32(float v) {
    #pragma unroll
    for (int m = 16; m > 0; m >>= 1) v += __shfl_xor(v, m, 64);
    return v;
}

// ---------------- CSR build ----------------
__global__ void count_kernel(const int* __restrict__ dst, int* __restrict__ cnt) {
    int i = blockIdx.x * blockDim.x + threadIdx.x;
    if (i < R_ * E_) {
        int r = i / E_;
        atomicAdd(&cnt[r * N_ + dst[i]], 1);
    }
}

__global__ __launch_bounds__(1024)
void scan_kernel(const int* __restrict__ cnt, int* __restrict__ rowptr, int* __restrict__ cursor) {
    const int r = blockIdx.x;
    const int t = threadIdx.x;
    const int CH = 20;               // 1024*20 >= 20000
    int local[CH];
    int s = 0;
    int b0 = t * CH;
    #pragma unroll
    for (int i = 0; i < CH; i++) {
        int idx = b0 + i;
        int v = (idx < N_) ? cnt[r * N_ + idx] : 0;
        local[i] = s;                // exclusive within thread
        s += v;
    }
    __shared__ int ts[1024];
    ts[t] = s;
    __syncthreads();
    for (int off = 1; off < 1024; off <<= 1) {
        int v = (t >= off) ? ts[t - off] : 0;
        __syncthreads();
        ts[t] += v;
        __syncthreads();
    }
    int texcl = ts[t] - s;
    #pragma unroll
    for (int i = 0; i < CH; i++) {
        int idx = b0 + i;
        if (idx < N_) {
            int p = texcl + local[i];
            rowptr[r * (N_ + 1) + idx] = p;
            cursor[r * N_ + idx] = p;
        }
    }
    if (t == 1023) rowptr[r * (N_ + 1) + N_] = ts[1023];
}

__global__ void fill_kernel(const int* __restrict__ src, const int* __restrict__ dst,
                            int* __restrict__ cursor, int* __restrict__ csr,
                            int* __restrict__ posmap) {
    int i = blockIdx.x * blockDim.x + threadIdx.x;
    if (i < R_ * E_) {
        int r = i / E_;
        int d = dst[i];
        int pos = atomicAdd(&cursor[r * N_ + d], 1);   // relation-local slot
        csr[r * E_ + pos] = src[i];
        posmap[i] = pos;
    }
}

// ---------------- tiny relation-embedding kernels ----------------
__global__ void ra_kernel(const float* __restrict__ re, const float* __restrict__ Wr,
                          float* __restrict__ ra, int relin) {
    int r = blockIdx.x, c = threadIdx.x;  // 256 threads
    float a = 0.f;
    for (int i = 0; i < relin; i++) a += re[r * relin + i] * Wr[(r * relin + i) * 256 + c];
    ra[r * 256 + c] = a;
}

__global__ void prop_kernel(const float* __restrict__ re, const float* __restrict__ Wp,
                            const float* __restrict__ bp, float* __restrict__ out, int relin) {
    int r = blockIdx.x, o = threadIdx.x;  // 128
    float a = bp[r * 128 + o];
    for (int i = 0; i < relin; i++) a += re[r * relin + i] * Wp[(r * relin + i) * 128 + o];
    out[r * 128 + o] = a;
}

__global__ void rp_kernel(const float* __restrict__ re2, const float* __restrict__ Wrf,
                          float* __restrict__ rp) {
    int r = blockIdx.x, t = threadIdx.x, h = t >> 5, d = t & 31;
    float a = 0.f;
    #pragma unroll
    for (int c = 0; c < 32; c++)
        a += re2[r * 128 + h * 32 + c] * Wrf[(((r * H_ + h) * D_) + c) * D_ + d];
    rp[r * 128 + t] = a;
}

// ---------------- register-tiled GEMM (projection): 128x128 tile, 8x8/thread ----------------
__global__ __launch_bounds__(256)
void gemm_tile(const float* __restrict__ X, int ldrows, int nrows,
               const float* __restrict__ W, const float* __restrict__ bias,
               float* __restrict__ Y) {
    const int t  = threadIdx.x;
    const int tx = t & 15;
    const int ty = t >> 4;
    const int r  = blockIdx.y;
    const int row0 = blockIdx.x * 128;

    const float* Xrel = X + (size_t)r * ldrows * 128;
    float*       Yrel = Y + (size_t)r * NP_ * 128;

    __shared__ float As[32][132];     // transposed, padded (+4) vs bank conflicts
    __shared__ float Bs[32][128];

    float acc[8][8];
    #pragma unroll
    for (int i = 0; i < 8; i++)
        #pragma unroll
        for (int j = 0; j < 8; j++) acc[i][j] = 0.f;

    const int kq = t & 7;
    for (int kb = 0; kb < 128; kb += 32) {
        __syncthreads();
        #pragma unroll
        for (int j = 0; j < 4; j++) {
            int rowl = (t >> 3) + 32 * j;
            int rowg = row0 + rowl;
            int rowc = rowg < nrows ? rowg : nrows - 1;
            float4 v = *(const float4*)&Xrel[(size_t)rowc * 128 + kb + kq * 4];
            As[kq * 4 + 0][rowl] = v.x;
            As[kq * 4 + 1][rowl] = v.y;
            As[kq * 4 + 2][rowl] = v.z;
            As[kq * 4 + 3][rowl] = v.w;
        }
        #pragma unroll
        for (int j = 0; j < 4; j++) {
            int fi = t + 256 * j;
            int kk = fi >> 5;
            int colq = fi & 31;
            *(float4*)&Bs[kk][colq * 4] = *(const float4*)&W[(size_t)(kb + kk) * 128 + colq * 4];
        }
        __syncthreads();
        #pragma unroll 8
        for (int k = 0; k < 32; k++) {
            float a[8], b[8];
            *(float4*)&a[0] = *(const float4*)&As[k][ty * 8];
            *(float4*)&a[4] = *(const float4*)&As[k][ty * 8 + 4];
            *(float4*)&b[0] = *(const float4*)&Bs[k][tx * 8];
            *(float4*)&b[4] = *(const float4*)&Bs[k][tx * 8 + 4];
            #pragma unroll
            for (int i = 0; i < 8; i++)
                #pragma unroll
                for (int j = 0; j < 8; j++) acc[i][j] += a[i] * b[j];
        }
    }

    const int col0 = tx * 8;
    float bq[8];
    #pragma unroll
    for (int j = 0; j < 8; j++) bq[j] = bias ? bias[col0 + j] : 0.f;
    #pragma unroll
    for (int i = 0; i < 8; i++) {
        int row = row0 + ty * 8 + i;
        float4 o0 = {acc[i][0] + bq[0], acc[i][1] + bq[1], acc[i][2] + bq[2], acc[i][3] + bq[3]};
        float4 o1 = {acc[i][4] + bq[4], acc[i][5] + bq[5], acc[i][6] + bq[6], acc[i][7] + bq[7]};
        *(float4*)&Yrel[(size_t)row * 128 + col0]     = o0;
        *(float4*)&Yrel[(size_t)row * 128 + col0 + 4] = o1;
    }
}

// ---------------- fused dual GEMM: 128x256 tile (Wres | Wn), 512 threads ----------------
// Ya = X@Wa + ba (residual), Yb = X@Wb (messages) + attention dots from acc.
__global__ __launch_bounds__(512)
void gemm_dual(const float* __restrict__ X, int ldrows, int nrows,
               const float* __restrict__ Wa, const float* __restrict__ ba,
               float* __restrict__ Ya,
               const float* __restrict__ Wb, float* __restrict__ Yb,
               const float* __restrict__ ra, float* __restrict__ esrc,
               float* __restrict__ edst) {
    const int t  = threadIdx.x;
    const int tx = t & 31;            // 32 col groups of 8 (0-15 -> Wa, 16-31 -> Wb)
    const int ty = t >> 5;            // 16 row groups of 8
    const int r  = blockIdx.y;
    const int row0 = blockIdx.x * 128;

    const float* Xrel = X + (size_t)r * ldrows * 128;

    __shared__ float As[32][132];     // transposed, padded
    __shared__ float Bs[32][256];     // [k][col]: cols 0-127 Wa, 128-255 Wb

    float acc[8][8];
    #pragma unroll
    for (int i = 0; i < 8; i++)
        #pragma unroll
        for (int j = 0; j < 8; j++) acc[i][j] = 0.f;

    const int kq = t & 7;
    for (int kb = 0; kb < 128; kb += 32) {
        __syncthreads();
        // stage A: 128 rows x 32 k, transposed
        #pragma unroll
        for (int j = 0; j < 2; j++) {
            int rowl = (t >> 3) + 64 * j;
            int rowg = row0 + rowl;
            int rowc = rowg < nrows ? rowg : nrows - 1;
            float4 v = *(const float4*)&Xrel[(size_t)rowc * 128 + kb + kq * 4];
            As[kq * 4 + 0][rowl] = v.x;
            As[kq * 4 + 1][rowl] = v.y;
            As[kq * 4 + 2][rowl] = v.z;
            As[kq * 4 + 3][rowl] = v.w;
        }
        // stage B: 32 k x 256 cols (Wa | Wb)
        #pragma unroll
        for (int j = 0; j < 4; j++) {
            int fi = t + 512 * j;
            int kk = fi >> 6;
            int colq = fi & 63;
            float4 v = (colq < 32)
                ? *(const float4*)&Wa[(size_t)(kb + kk) * 128 + colq * 4]
                : *(const float4*)&Wb[(size_t)(kb + kk) * 128 + (colq - 32) * 4];
            *(float4*)&Bs[kk][colq * 4] = v;
        }
        __syncthreads();
        #pragma unroll 8
        for (int k = 0; k < 32; k++) {
            float a[8], b[8];
            *(float4*)&a[0] = *(const float4*)&As[k][ty * 8];
            *(float4*)&a[4] = *(const float4*)&As[k][ty * 8 + 4];
            *(float4*)&b[0] = *(const float4*)&Bs[k][tx * 8];
            *(float4*)&b[4] = *(const float4*)&Bs[k][tx * 8 + 4];
            #pragma unroll
            for (int i = 0; i < 8; i++)
                #pragma unroll
                for (int j = 0; j < 8; j++) acc[i][j] += a[i] * b[j];
        }
    }

    if (tx < 16) {                    // residual half
        const int col0 = tx * 8;
        float bq[8];
        #pragma unroll
        for (int j = 0; j < 8; j++) bq[j] = ba[col0 + j];
        float* Yrel = Ya + (size_t)r * NP_ * 128;
        #pragma unroll
        for (int i = 0; i < 8; i++) {
            int row = row0 + ty * 8 + i;
            float4 o0 = {acc[i][0] + bq[0], acc[i][1] + bq[1], acc[i][2] + bq[2], acc[i][3] + bq[3]};
            float4 o1 = {acc[i][4] + bq[4], acc[i][5] + bq[5], acc[i][6] + bq[6], acc[i][7] + bq[7]};
            *(float4*)&Yrel[(size_t)row * 128 + col0]     = o0;
            *(float4*)&Yrel[(size_t)row * 128 + col0 + 4] = o1;
        }
    } else {                          // message half + attention dots
        const int col0 = (tx - 16) * 8;
        float* Yrel = Yb + (size_t)r * NP_ * 128;
        #pragma unroll
        for (int i = 0; i < 8; i++) {
            int row = row0 + ty * 8 + i;
            float4 o0 = {acc[i][0], acc[i][1], acc[i][2], acc[i][3]};
            float4 o1 = {acc[i][4], acc[i][5], acc[i][6], acc[i][7]};
            *(float4*)&Yrel[(size_t)row * 128 + col0]     = o0;
            *(float4*)&Yrel[(size_t)row * 128 + col0 + 4] = o1;
        }
        const int hh = (tx - 16) >> 2;
        float rad[8], ras[8];
        #pragma unroll
        for (int j = 0; j < 8; j++) {
            int c = ((tx - 16) & 3) * 8 + j;
            rad[j] = ra[(r * H_ + hh) * 64 + c];
            ras[j] = ra[(r * H_ + hh) * 64 + 32 + c];
        }
        #pragma unroll
        for (int i = 0; i < 8; i++) {
            float vd = 0.f, vs = 0.f;
            #pragma unroll
            for (int j = 0; j < 8; j++) { vd += acc[i][j] * rad[j]; vs += acc[i][j] * ras[j]; }
            vd += __shfl_xor(vd, 1); vd += __shfl_xor(vd, 2);
            vs += __shfl_xor(vs, 1); vs += __shfl_xor(vs, 2);
            if (((tx - 16) & 3) == 0) {
                int row = row0 + ty * 8 + i;
                edst[((size_t)r * NP_ + row) * 4 + hh] = vd;
                esrc[((size_t)r * NP_ + row) * 4 + hh] = vs;
            }
        }
    }
}

// ---------------- edge-parallel attention numerator ----------------
__global__ void edgep_kernel(const int* __restrict__ src, const int* __restrict__ dst,
                             const int* __restrict__ posmap,
                             const float* __restrict__ esrc, const float* __restrict__ edst,
                             float4* __restrict__ pbuf) {
    int i = blockIdx.x * blockDim.x + threadIdx.x;
    if (i >= R_ * E_) return;
    int r = i / E_;
    int s = src[i], d = dst[i];
    const float4 es = *(const float4*)&esrc[((size_t)r * NP_ + s) * 4];
    const float4 ed = *(const float4*)&edst[((size_t)r * NP_ + d) * 4];
    float4 p;
    p.x = __expf(leaky(es.x + ed.x));
    p.y = __expf(leaky(es.y + ed.y));
    p.z = __expf(leaky(es.z + ed.z));
    p.w = __expf(leaky(es.w + ed.w));
    pbuf[(size_t)r * E_ + posmap[i]] = p;
}

// ---------------- aggregation: acc += p * h[src], + relu + residual gate ----------------
__global__ __launch_bounds__(128)
void aggregate(const float* __restrict__ hbuf, const float* __restrict__ pbuf,
               const int* __restrict__ rowptr, const int* __restrict__ csr,
               const float* __restrict__ resw, float* __restrict__ io) {
    const int n = blockIdx.x, r = blockIdx.y;
    const int t = threadIdx.x;
    const int lane32 = t & 31;        // channel quad index
    const int slot = t >> 5;          // edge slot 0..3
    const int h = lane32 >> 3;        // head of this channel quad
    const int beg = rowptr[r * (N_ + 1) + n];
    const int end = rowptr[r * (N_ + 1) + n + 1];

    float4 acc = {0.f, 0.f, 0.f, 0.f};
    float psum = 0.f;
    for (int j0 = beg; j0 < end; j0 += 4) {
        int j = j0 + slot;
        bool valid = j < end;
        int jc = valid ? j : beg;
        int s = csr[r * E_ + jc];
        float p = valid ? pbuf[((size_t)r * E_ + j) * 4 + h] : 0.f;
        const float4 hv = *(const float4*)&hbuf[((size_t)r * NP_ + s) * 128 + lane32 * 4];
        acc.x += p * hv.x; acc.y += p * hv.y; acc.z += p * hv.z; acc.w += p * hv.w;
        psum += p;
    }

    __shared__ float4 sacc[4][32];
    __shared__ float spsum[4][32];
    sacc[slot][lane32] = acc;
    spsum[slot][lane32] = psum;
    __syncthreads();
    if (t < 32) {
        float4 a0 = sacc[0][t], a1 = sacc[1][t], a2 = sacc[2][t], a3 = sacc[3][t];
        float ps = spsum[0][t] + spsum[1][t] + spsum[2][t] + spsum[3][t];
        float inv = 1.f / (ps + 1e-16f);
        float alpha = 1.f / (1.f + __expf(-resw[0]));
        float4* iop = (float4*)&io[((size_t)r * NP_ + n) * 128 + t * 4];
        float4 res = *iop;
        float4 o;
        o.x = fmaxf((a0.x + a1.x + a2.x + a3.x) * inv, 0.f) * alpha + res.x * (1.f - alpha);
        o.y = fmaxf((a0.y + a1.y + a2.y + a3.y) * inv, 0.f) * alpha + res.y * (1.f - alpha);
        o.z = fmaxf((a0.z + a1.z + a2.z + a3.z) * inv, 0.f) * alpha + res.z * (1.f - alpha);
        o.w = fmaxf((a0.w + a1.w + a2.w + a3.w) * inv, 0.f) * alpha + res.w * (1.f - alpha);
        *iop = o;
    }
}

// ---------------- cross-relation attention ----------------
__global__ __launch_bounds__(128)
void cross_kernel(const float* __restrict__ fin, const float* __restrict__ Wx,
                  float* __restrict__ fout) {
    const int n = blockIdx.x, t = threadIdx.x;
    float f[3];
    #pragma unroll
    for (int r = 0; r < 3; r++) f[r] = fin[((size_t)r * NP_ + n) * 128 + t];
    #pragma unroll
    for (int k = 0; k < 3; k++) {
        float w = Wx[k * 128 + t];
        float s[3];
        #pragma unroll
        for (int r = 0; r < 3; r++) s[r] = leaky(red32(f[r] * w));
        float mx = fmaxf(s[0], fmaxf(s[1], s[2]));
        float a0 = __expf(s[0] - mx), a1 = __expf(s[1] - mx), a2 = __expf(s[2] - mx);
        float den = a0 + a1 + a2;
        fout[((size_t)k * NP_ + n) * 128 + t] = (f[0] * a0 + f[1] * a1 + f[2] * a2) / den;
    }
}

// ---------------- relation fusing ----------------
__global__ __launch_bounds__(128)
void fuse_kernel(const float* __restrict__ fin, const float* __restrict__ Wnf,
                 const float* __restrict__ rp, float* __restrict__ out) {
    const int n = blockIdx.x, t = threadIdx.x, h = t >> 5, e = t & 31;
    __shared__ float sf[3][128];
    #pragma unroll
    for (int r = 0; r < 3; r++) sf[r][t] = fin[((size_t)r * NP_ + n) * 128 + t];
    __syncthreads();
    float hf[3];
    #pragma unroll
    for (int r = 0; r < 3; r++) {
        float a = 0.f;
        #pragma unroll
        for (int d = 0; d < 32; d++)
            a += sf[r][h * 32 + d] * Wnf[(((r * H_ + h) * D_) + d) * D_ + e];
        hf[r] = a;
    }
    float s[3];
    #pragma unroll
    for (int r = 0; r < 3; r++) s[r] = leaky(red32(hf[r] * rp[(r * H_ + h) * D_ + e]));
    float mx = fmaxf(s[0], fmaxf(s[1], s[2]));
    float a0 = __expf(s[0] - mx), a1 = __expf(s[1] - mx), a2 = __expf(s[2] - mx);
    float den = a0 + a1 + a2;
    out[(size_t)n * 128 + t] = (hf[0] * a0 + hf[1] * a1 + hf[2] * a2) / den;
}

extern "C" void kernel_launch(void* const* d_in, const int* in_sizes, int n_in,
                              void* d_out, int out_size, void* d_ws, size_t ws_size,
                              hipStream_t stream) {
    const float* x        = (const float*)d_in[0];
    const int*   src      = (const int*)d_in[1];
    const int*   dst      = (const int*)d_in[2];
    const float* proj_W   = (const float*)d_in[3];
    const float* proj_b   = (const float*)d_in[4];
    const float* rel_emb0 = (const float*)d_in[5];
    const float* Wn0      = (const float*)d_in[6];
    const float* Wr0      = (const float*)d_in[7];
    const float* Wp0      = (const float*)d_in[8];
    const float* bp0      = (const float*)d_in[9];
    const float* Wres0    = (const float*)d_in[10];
    const float* bres0    = (const float*)d_in[11];
    const float* resw0    = (const float*)d_in[12];
    const float* Wx0      = (const float*)d_in[13];
    const float* Wn1      = (const float*)d_in[14];
    const float* Wr1      = (const float*)d_in[15];
    const float* Wp1      = (const float*)d_in[16];
    const float* bp1      = (const float*)d_in[17];
    const float* Wres1    = (const float*)d_in[18];
    const float* bres1    = (const float*)d_in[19];
    const float* resw1    = (const float*)d_in[20];
    const float* Wx1      = (const float*)d_in[21];
    const float* Wnf      = (const float*)d_in[22];
    const float* Wrf      = (const float*)d_in[23];

    char* ws = (char*)d_ws;
    size_t off = 0;
    auto alloc = [&](size_t bytes) { char* p = ws + off; off = (off + bytes + 255) & ~(size_t)255; return p; };
    const size_t BIG = (size_t)R_ * NP_ * 128 * sizeof(float);
    float* xp    = (float*)alloc(BIG);
    float* bufA  = (float*)alloc(BIG);   // residual (X@Wres+b) -> layer output
    float* bufB  = (float*)alloc(BIG);   // cross output / next-layer input
    float* hbuf  = (float*)alloc(BIG);   // messages (X@Wn)
    float* pbuf  = (float*)alloc((size_t)R_ * E_ * 4 * sizeof(float));
    int*   posmap= (int*)alloc((size_t)R_ * E_ * sizeof(int));
    float* esrc  = (float*)alloc((size_t)R_ * NP_ * H_ * sizeof(float));
    float* edst  = (float*)alloc((size_t)R_ * NP_ * H_ * sizeof(float));
    int*   cnt   = (int*)alloc((size_t)R_ * N_ * sizeof(int));
    int*   cursor= (int*)alloc((size_t)R_ * N_ * sizeof(int));
    int*   rowptr= (int*)alloc((size_t)R_ * (N_ + 1) * sizeof(int));
    int*   csr   = (int*)alloc((size_t)R_ * E_ * sizeof(int));
    float* remb1 = (float*)alloc((size_t)R_ * 128 * sizeof(float));
    float* remb2 = (float*)alloc((size_t)R_ * 128 * sizeof(float));
    float* ra0   = (float*)alloc((size_t)R_ * 256 * sizeof(float));
    float* ra1   = (float*)alloc((size_t)R_ * 256 * sizeof(float));
    float* rpb   = (float*)alloc((size_t)R_ * 128 * sizeof(float));

    // ---- CSR build (shared by both layers) ----
    hipMemsetAsync(cnt, 0, (size_t)R_ * N_ * sizeof(int), stream);
    const int EB = (R_ * E_ + 255) / 256;
    count_kernel<<<EB, 256, 0, stream>>>(dst, cnt);
    scan_kernel<<<R_, 1024, 0, stream>>>(cnt, rowptr, cursor);
    fill_kernel<<<EB, 256, 0, stream>>>(src, dst, cursor, csr, posmap);

    // ---- relation-embedding chain ----
    ra_kernel<<<R_, 256, 0, stream>>>(rel_emb0, Wr0, ra0, 64);
    prop_kernel<<<R_, 128, 0, stream>>>(rel_emb0, Wp0, bp0, remb1, 64);
    ra_kernel<<<R_, 256, 0, stream>>>(remb1, Wr1, ra1, 128);
    prop_kernel<<<R_, 128, 0, stream>>>(remb1, Wp1, bp1, remb2, 128);
    rp_kernel<<<R_, 128, 0, stream>>>(remb2, Wrf, rpb);

    const dim3 GT(NP_ / 128, R_);   // 157 x 3 tile blocks
    // ---- projection ----
    gemm_tile<<<GT, 256, 0, stream>>>(x, N_, N_, proj_W, proj_b, xp);
    // ---- layer 0 ----
    gemm_dual<<<GT, 512, 0, stream>>>(xp, NP_, NP_, Wres0, bres0, bufA,
                                      Wn0, hbuf, ra0, esrc, edst);
    edgep_kernel<<<EB, 256, 0, stream>>>(src, dst, posmap, esrc, edst, (float4*)pbuf);
    aggregate<<<dim3(N_, R_), 128, 0, stream>>>(hbuf, pbuf, rowptr, csr, resw0, bufA);
    cross_kernel<<<N_, 128, 0, stream>>>(bufA, Wx0, bufB);
    // ---- layer 1 ----
    gemm_dual<<<GT, 512, 0, stream>>>(bufB, NP_, NP_, Wres1, bres1, bufA,
                                      Wn1, hbuf, ra1, esrc, edst);
    edgep_kernel<<<EB, 256, 0, stream>>>(src, dst, posmap, esrc, edst, (float4*)pbuf);
    aggregate<<<dim3(N_, R_), 128, 0, stream>>>(hbuf, pbuf, rowptr, csr, resw1, bufA);
    cross_kernel<<<N_, 128, 0, stream>>>(bufA, Wx1, xp);
    // ---- relation fusing ----
    fuse_kernel<<<N_, 128, 0, stream>>>(xp, Wnf, rpb, (float*)d_out);
}

// Round 11
// 659.407 us; speedup vs baseline: 1.0820x; 1.0422x over previous
//
#include <hip/hip_runtime.h>
#include <hip/hip_bf16.h>

#define R_ 3
#define N_ 20000
#define NP_ 20096          // padded rows per relation (157 * 128)
#define E_ 250000
#define H_ 4
#define D_ 32
#define IN_ 128
#define NEG_ 0.2f

static __device__ __forceinline__ float leaky(float v) { return v >= 0.f ? v : NEG_ * v; }

static __device__ __forceinline__ float red32(float v) {
    #pragma unroll
    for (int m = 16; m > 0; m >>= 1) v += __shfl_xor(v, m, 64);
    return v;
}

// ---------------- CSR build ----------------
__global__ void count_kernel(const int* __restrict__ dst, int* __restrict__ cnt) {
    int i = blockIdx.x * blockDim.x + threadIdx.x;
    if (i < R_ * E_) {
        int r = i / E_;
        atomicAdd(&cnt[r * N_ + dst[i]], 1);
    }
}

__global__ __launch_bounds__(1024)
void scan_kernel(const int* __restrict__ cnt, int* __restrict__ rowptr, int* __restrict__ cursor) {
    const int r = blockIdx.x;
    const int t = threadIdx.x;
    const int CH = 20;               // 1024*20 >= 20000
    int local[CH];
    int s = 0;
    int b0 = t * CH;
    #pragma unroll
    for (int i = 0; i < CH; i++) {
        int idx = b0 + i;
        int v = (idx < N_) ? cnt[r * N_ + idx] : 0;
        local[i] = s;                // exclusive within thread
        s += v;
    }
    __shared__ int ts[1024];
    ts[t] = s;
    __syncthreads();
    for (int off = 1; off < 1024; off <<= 1) {
        int v = (t >= off) ? ts[t - off] : 0;
        __syncthreads();
        ts[t] += v;
        __syncthreads();
    }
    int texcl = ts[t] - s;
    #pragma unroll
    for (int i = 0; i < CH; i++) {
        int idx = b0 + i;
        if (idx < N_) {
            int p = texcl + local[i];
            rowptr[r * (N_ + 1) + idx] = p;
            cursor[r * N_ + idx] = p;
        }
    }
    if (t == 1023) rowptr[r * (N_ + 1) + N_] = ts[1023];
}

__global__ void fill_kernel(const int* __restrict__ src, const int* __restrict__ dst,
                            int* __restrict__ cursor, int* __restrict__ csr,
                            int* __restrict__ posmap) {
    int i = blockIdx.x * blockDim.x + threadIdx.x;
    if (i < R_ * E_) {
        int r = i / E_;
        int d = dst[i];
        int pos = atomicAdd(&cursor[r * N_ + d], 1);   // relation-local slot
        csr[r * E_ + pos] = src[i];
        posmap[i] = pos;
    }
}

// ---------------- tiny relation-embedding kernels ----------------
__global__ void ra_kernel(const float* __restrict__ re, const float* __restrict__ Wr,
                          float* __restrict__ ra, int relin) {
    int r = blockIdx.x, c = threadIdx.x;  // 256 threads
    float a = 0.f;
    for (int i = 0; i < relin; i++) a += re[r * relin + i] * Wr[(r * relin + i) * 256 + c];
    ra[r * 256 + c] = a;
}

__global__ void prop_kernel(const float* __restrict__ re, const float* __restrict__ Wp,
                            const float* __restrict__ bp, float* __restrict__ out, int relin) {
    int r = blockIdx.x, o = threadIdx.x;  // 128
    float a = bp[r * 128 + o];
    for (int i = 0; i < relin; i++) a += re[r * relin + i] * Wp[(r * relin + i) * 128 + o];
    out[r * 128 + o] = a;
}

__global__ void rp_kernel(const float* __restrict__ re2, const float* __restrict__ Wrf,
                          float* __restrict__ rp) {
    int r = blockIdx.x, t = threadIdx.x, h = t >> 5, d = t & 31;
    float a = 0.f;
    #pragma unroll
    for (int c = 0; c < 32; c++)
        a += re2[r * 128 + h * 32 + c] * Wrf[(((r * H_ + h) * D_) + c) * D_ + d];
    rp[r * 128 + t] = a;
}

// ---------------- projection folding: Wc = P @ W, bc = pb @ W (+ bin) ----------------
__global__ void combine_W(const float* __restrict__ P, const float* __restrict__ W,
                          float* __restrict__ Wc) {
    const int i = blockIdx.x, j = threadIdx.x;   // 128 x 128
    float a = 0.f;
    #pragma unroll 8
    for (int k = 0; k < 128; k++) a += P[i * 128 + k] * W[k * 128 + j];
    Wc[i * 128 + j] = a;
}

__global__ void combine_b(const float* __restrict__ pb, const float* __restrict__ W,
                          const float* __restrict__ bin, float* __restrict__ bc) {
    const int j = threadIdx.x;                   // 128
    float a = bin ? bin[j] : 0.f;
    #pragma unroll 8
    for (int k = 0; k < 128; k++) a += pb[k] * W[k * 128 + j];
    bc[j] = a;
}

// ---------------- fused dual GEMM: 128x256 tile (Wa | Wb), 512 threads ----------------
// Ya = X@Wa + ba (residual), Yb = X@Wb (+bb) (messages) + attention dots.
// Col-split ownership: thread owns Wa cols [tx*4, tx*4+4) and Wb cols [tx*4, tx*4+4)
// so each Bs fragment read is part of a contiguous 512B wave read (bank-conflict-free).
__global__ __launch_bounds__(512)
void gemm_dual(const float* __restrict__ X, int ldrows, int nrows,
               const float* __restrict__ Wa, const float* __restrict__ ba,
               float* __restrict__ Ya,
               const float* __restrict__ Wb, const float* __restrict__ bb,
               float* __restrict__ Yb,
               const float* __restrict__ ra, float* __restrict__ esrc,
               float* __restrict__ edst) {
    const int t  = threadIdx.x;
    const int tx = t & 31;            // 32 col quads
    const int ty = t >> 5;            // 16 row groups of 8
    const int r  = blockIdx.y;
    const int row0 = blockIdx.x * 128;

    const float* Xrel = X + (size_t)r * ldrows * 128;

    __shared__ float As[32][132];     // transposed, padded
    __shared__ float Bs[32][256];     // [k][col]: cols 0-127 Wa, 128-255 Wb

    float acc[8][8];
    #pragma unroll
    for (int i = 0; i < 8; i++)
        #pragma unroll
        for (int j = 0; j < 8; j++) acc[i][j] = 0.f;

    const int kq = t & 7;
    for (int kb = 0; kb < 128; kb += 32) {
        __syncthreads();
        // stage A: 128 rows x 32 k, transposed
        #pragma unroll
        for (int j = 0; j < 2; j++) {
            int rowl = (t >> 3) + 64 * j;
            int rowg = row0 + rowl;
            int rowc = rowg < nrows ? rowg : nrows - 1;
            float4 v = *(const float4*)&Xrel[(size_t)rowc * 128 + kb + kq * 4];
            As[kq * 4 + 0][rowl] = v.x;
            As[kq * 4 + 1][rowl] = v.y;
            As[kq * 4 + 2][rowl] = v.z;
            As[kq * 4 + 3][rowl] = v.w;
        }
        // stage B: 32 k x 256 cols (Wa | Wb), contiguous per-wave writes
        #pragma unroll
        for (int j = 0; j < 4; j++) {
            int fi = t + 512 * j;
            int kk = fi >> 6;
            int colq = fi & 63;
            float4 v = (colq < 32)
                ? *(const float4*)&Wa[(size_t)(kb + kk) * 128 + colq * 4]
                : *(const float4*)&Wb[(size_t)(kb + kk) * 128 + (colq - 32) * 4];
            *(float4*)&Bs[kk][colq * 4] = v;
        }
        __syncthreads();
        #pragma unroll 8
        for (int k = 0; k < 32; k++) {
            float a[8], b[8];
            *(float4*)&a[0] = *(const float4*)&As[k][ty * 8];
            *(float4*)&a[4] = *(const float4*)&As[k][ty * 8 + 4];
            *(float4*)&b[0] = *(const float4*)&Bs[k][tx * 4];         // Wa quad
            *(float4*)&b[4] = *(const float4*)&Bs[k][tx * 4 + 128];   // Wb quad
            #pragma unroll
            for (int i = 0; i < 8; i++)
                #pragma unroll
                for (int j = 0; j < 8; j++) acc[i][j] += a[i] * b[j];
        }
    }

    const int col0 = tx * 4;
    float baq[4], bbq[4];
    #pragma unroll
    for (int j = 0; j < 4; j++) {
        baq[j] = ba[col0 + j];
        bbq[j] = bb ? bb[col0 + j] : 0.f;
    }
    #pragma unroll
    for (int i = 0; i < 8; i++)
        #pragma unroll
        for (int j = 0; j < 4; j++) {
            acc[i][j]     += baq[j];
            acc[i][4 + j] += bbq[j];
        }

    float* Yar = Ya + (size_t)r * NP_ * 128;
    float* Ybr = Yb + (size_t)r * NP_ * 128;
    const int hh = tx >> 3;           // head of this col quad
    float rad[4], ras[4];
    #pragma unroll
    for (int j = 0; j < 4; j++) {
        int c = (tx & 7) * 4 + j;     // col within head
        rad[j] = ra[(r * H_ + hh) * 64 + c];
        ras[j] = ra[(r * H_ + hh) * 64 + 32 + c];
    }
    #pragma unroll
    for (int i = 0; i < 8; i++) {
        int row = row0 + ty * 8 + i;
        float4 oa = {acc[i][0], acc[i][1], acc[i][2], acc[i][3]};
        float4 ob = {acc[i][4], acc[i][5], acc[i][6], acc[i][7]};
        *(float4*)&Yar[(size_t)row * 128 + col0] = oa;
        *(float4*)&Ybr[(size_t)row * 128 + col0] = ob;
        float vd = 0.f, vs = 0.f;
        #pragma unroll
        for (int j = 0; j < 4; j++) { vd += acc[i][4 + j] * rad[j]; vs += acc[i][4 + j] * ras[j]; }
        vd += __shfl_xor(vd, 1); vd += __shfl_xor(vd, 2); vd += __shfl_xor(vd, 4);
        vs += __shfl_xor(vs, 1); vs += __shfl_xor(vs, 2); vs += __shfl_xor(vs, 4);
        if ((tx & 7) == 0) {
            edst[((size_t)r * NP_ + row) * 4 + hh] = vd;
            esrc[((size_t)r * NP_ + row) * 4 + hh] = vs;
        }
    }
}

// ---------------- edge-parallel attention numerator ----------------
__global__ void edgep_kernel(const int* __restrict__ src, const int* __restrict__ dst,
                             const int* __restrict__ posmap,
                             const float* __restrict__ esrc, const float* __restrict__ edst,
                             float4* __restrict__ pbuf) {
    int i = blockIdx.x * blockDim.x + threadIdx.x;
    if (i >= R_ * E_) return;
    int r = i / E_;
    int s = src[i], d = dst[i];
    const float4 es = *(const float4*)&esrc[((size_t)r * NP_ + s) * 4];
    const float4 ed = *(const float4*)&edst[((size_t)r * NP_ + d) * 4];
    float4 p;
    p.x = __expf(leaky(es.x + ed.x));
    p.y = __expf(leaky(es.y + ed.y));
    p.z = __expf(leaky(es.z + ed.z));
    p.w = __expf(leaky(es.w + ed.w));
    pbuf[(size_t)r * E_ + posmap[i]] = p;
}

// ---------------- aggregation: acc += p * h[src], + relu + residual gate ----------------
__global__ __launch_bounds__(128)
void aggregate(const float* __restrict__ hbuf, const float* __restrict__ pbuf,
               const int* __restrict__ rowptr, const int* __restrict__ csr,
               const float* __restrict__ resw, float* __restrict__ io) {
    const int n = blockIdx.x, r = blockIdx.y;
    const int t = threadIdx.x;
    const int lane32 = t & 31;        // channel quad index
    const int slot = t >> 5;          // edge slot 0..3
    const int h = lane32 >> 3;        // head of this channel quad
    const int beg = rowptr[r * (N_ + 1) + n];
    const int end = rowptr[r * (N_ + 1) + n + 1];

    float4 acc = {0.f, 0.f, 0.f, 0.f};
    float psum = 0.f;
    for (int j0 = beg; j0 < end; j0 += 4) {
        int j = j0 + slot;
        bool valid = j < end;
        int jc = valid ? j : beg;
        int s = csr[r * E_ + jc];
        float p = valid ? pbuf[((size_t)r * E_ + j) * 4 + h] : 0.f;
        const float4 hv = *(const float4*)&hbuf[((size_t)r * NP_ + s) * 128 + lane32 * 4];
        acc.x += p * hv.x; acc.y += p * hv.y; acc.z += p * hv.z; acc.w += p * hv.w;
        psum += p;
    }

    __shared__ float4 sacc[4][32];
    __shared__ float spsum[4][32];
    sacc[slot][lane32] = acc;
    spsum[slot][lane32] = psum;
    __syncthreads();
    if (t < 32) {
        float4 a0 = sacc[0][t], a1 = sacc[1][t], a2 = sacc[2][t], a3 = sacc[3][t];
        float ps = spsum[0][t] + spsum[1][t] + spsum[2][t] + spsum[3][t];
        float inv = 1.f / (ps + 1e-16f);
        float alpha = 1.f / (1.f + __expf(-resw[0]));
        float4* iop = (float4*)&io[((size_t)r * NP_ + n) * 128 + t * 4];
        float4 res = *iop;
        float4 o;
        o.x = fmaxf((a0.x + a1.x + a2.x + a3.x) * inv, 0.f) * alpha + res.x * (1.f - alpha);
        o.y = fmaxf((a0.y + a1.y + a2.y + a3.y) * inv, 0.f) * alpha + res.y * (1.f - alpha);
        o.z = fmaxf((a0.z + a1.z + a2.z + a3.z) * inv, 0.f) * alpha + res.z * (1.f - alpha);
        o.w = fmaxf((a0.w + a1.w + a2.w + a3.w) * inv, 0.f) * alpha + res.w * (1.f - alpha);
        *iop = o;
    }
}

// ---------------- cross-relation attention ----------------
__global__ __launch_bounds__(128)
void cross_kernel(const float* __restrict__ fin, const float* __restrict__ Wx,
                  float* __restrict__ fout) {
    const int n = blockIdx.x, t = threadIdx.x;
    float f[3];
    #pragma unroll
    for (int r = 0; r < 3; r++) f[r] = fin[((size_t)r * NP_ + n) * 128 + t];
    #pragma unroll
    for (int k = 0; k < 3; k++) {
        float w = Wx[k * 128 + t];
        float s[3];
        #pragma unroll
        for (int r = 0; r < 3; r++) s[r] = leaky(red32(f[r] * w));
        float mx = fmaxf(s[0], fmaxf(s[1], s[2]));
        float a0 = __expf(s[0] - mx), a1 = __expf(s[1] - mx), a2 = __expf(s[2] - mx);
        float den = a0 + a1 + a2;
        fout[((size_t)k * NP_ + n) * 128 + t] = (f[0] * a0 + f[1] * a1 + f[2] * a2) / den;
    }
}

// ---------------- relation fusing ----------------
__global__ __launch_bounds__(128)
void fuse_kernel(const float* __restrict__ fin, const float* __restrict__ Wnf,
                 const float* __restrict__ rp, float* __restrict__ out) {
    const int n = blockIdx.x, t = threadIdx.x, h = t >> 5, e = t & 31;
    __shared__ float sf[3][128];
    #pragma unroll
    for (int r = 0; r < 3; r++) sf[r][t] = fin[((size_t)r * NP_ + n) * 128 + t];
    __syncthreads();
    float hf[3];
    #pragma unroll
    for (int r = 0; r < 3; r++) {
        float a = 0.f;
        #pragma unroll
        for (int d = 0; d < 32; d++)
            a += sf[r][h * 32 + d] * Wnf[(((r * H_ + h) * D_) + d) * D_ + e];
        hf[r] = a;
    }
    float s[3];
    #pragma unroll
    for (int r = 0; r < 3; r++) s[r] = leaky(red32(hf[r] * rp[(r * H_ + h) * D_ + e]));
    float mx = fmaxf(s[0], fmaxf(s[1], s[2]));
    float a0 = __expf(s[0] - mx), a1 = __expf(s[1] - mx), a2 = __expf(s[2] - mx);
    float den = a0 + a1 + a2;
    out[(size_t)n * 128 + t] = (hf[0] * a0 + hf[1] * a1 + hf[2] * a2) / den;
}

extern "C" void kernel_launch(void* const* d_in, const int* in_sizes, int n_in,
                              void* d_out, int out_size, void* d_ws, size_t ws_size,
                              hipStream_t stream) {
    const float* x        = (const float*)d_in[0];
    const int*   src      = (const int*)d_in[1];
    const int*   dst      = (const int*)d_in[2];
    const float* proj_W   = (const float*)d_in[3];
    const float* proj_b   = (const float*)d_in[4];
    const float* rel_emb0 = (const float*)d_in[5];
    const float* Wn0      = (const float*)d_in[6];
    const float* Wr0      = (const float*)d_in[7];
    const float* Wp0      = (const float*)d_in[8];
    const float* bp0      = (const float*)d_in[9];
    const float* Wres0    = (const float*)d_in[10];
    const float* bres0    = (const float*)d_in[11];
    const float* resw0    = (const float*)d_in[12];
    const float* Wx0      = (const float*)d_in[13];
    const float* Wn1      = (const float*)d_in[14];
    const float* Wr1      = (const float*)d_in[15];
    const float* Wp1      = (const float*)d_in[16];
    const float* bp1      = (const float*)d_in[17];
    const float* Wres1    = (const float*)d_in[18];
    const float* bres1    = (const float*)d_in[19];
    const float* resw1    = (const float*)d_in[20];
    const float* Wx1      = (const float*)d_in[21];
    const float* Wnf      = (const float*)d_in[22];
    const float* Wrf      = (const float*)d_in[23];

    char* ws = (char*)d_ws;
    size_t off = 0;
    auto alloc = [&](size_t bytes) { char* p = ws + off; off = (off + bytes + 255) & ~(size_t)255; return p; };
    const size_t BIG = (size_t)R_ * NP_ * 128 * sizeof(float);
    float* bufA  = (float*)alloc(BIG);   // residual (X@Wres+b) -> layer output
    float* bufB  = (float*)alloc(BIG);   // cross output / next-layer input
    float* hbuf  = (float*)alloc(BIG);   // messages (X@Wn)
    float* pbuf  = (float*)alloc((size_t)R_ * E_ * 4 * sizeof(float));
    int*   posmap= (int*)alloc((size_t)R_ * E_ * sizeof(int));
    float* esrc  = (float*)alloc((size_t)R_ * NP_ * H_ * sizeof(float));
    float* edst  = (float*)alloc((size_t)R_ * NP_ * H_ * sizeof(float));
    int*   cnt   = (int*)alloc((size_t)R_ * N_ * sizeof(int));
    int*   cursor= (int*)alloc((size_t)R_ * N_ * sizeof(int));
    int*   rowptr= (int*)alloc((size_t)R_ * (N_ + 1) * sizeof(int));
    int*   csr   = (int*)alloc((size_t)R_ * E_ * sizeof(int));
    float* remb1 = (float*)alloc((size_t)R_ * 128 * sizeof(float));
    float* remb2 = (float*)alloc((size_t)R_ * 128 * sizeof(float));
    float* ra0   = (float*)alloc((size_t)R_ * 256 * sizeof(float));
    float* ra1   = (float*)alloc((size_t)R_ * 256 * sizeof(float));
    float* rpb   = (float*)alloc((size_t)R_ * 128 * sizeof(float));
    float* Wres0c= (float*)alloc(128 * 128 * sizeof(float));
    float* Wn0c  = (float*)alloc(128 * 128 * sizeof(float));
    float* bres0c= (float*)alloc(128 * sizeof(float));
    float* bn0c  = (float*)alloc(128 * sizeof(float));

    // ---- CSR build (shared by both layers) ----
    hipMemsetAsync(cnt, 0, (size_t)R_ * N_ * sizeof(int), stream);
    const int EB = (R_ * E_ + 255) / 256;
    count_kernel<<<EB, 256, 0, stream>>>(dst, cnt);
    scan_kernel<<<R_, 1024, 0, stream>>>(cnt, rowptr, cursor);
    fill_kernel<<<EB, 256, 0, stream>>>(src, dst, cursor, csr, posmap);

    // ---- relation-embedding chain ----
    ra_kernel<<<R_, 256, 0, stream>>>(rel_emb0, Wr0, ra0, 64);
    prop_kernel<<<R_, 128, 0, stream>>>(rel_emb0, Wp0, bp0, remb1, 64);
    ra_kernel<<<R_, 256, 0, stream>>>(remb1, Wr1, ra1, 128);
    prop_kernel<<<R_, 128, 0, stream>>>(remb1, Wp1, bp1, remb2, 128);
    rp_kernel<<<R_, 128, 0, stream>>>(remb2, Wrf, rpb);

    // ---- fold projection into layer-0 weights ----
    combine_W<<<128, 128, 0, stream>>>(proj_W, Wres0, Wres0c);
    combine_b<<<1, 128, 0, stream>>>(proj_b, Wres0, bres0, bres0c);
    combine_W<<<128, 128, 0, stream>>>(proj_W, Wn0, Wn0c);
    combine_b<<<1, 128, 0, stream>>>(proj_b, Wn0, nullptr, bn0c);

    const dim3 GT(NP_ / 128, R_);   // 157 x 3 tile blocks
    // ---- layer 0 (projection folded) ----
    gemm_dual<<<GT, 512, 0, stream>>>(x, N_, N_, Wres0c, bres0c, bufA,
                                      Wn0c, bn0c, hbuf, ra0, esrc, edst);
    edgep_kernel<<<EB, 256, 0, stream>>>(src, dst, posmap, esrc, edst, (float4*)pbuf);
    aggregate<<<dim3(N_, R_), 128, 0, stream>>>(hbuf, pbuf, rowptr, csr, resw0, bufA);
    cross_kernel<<<N_, 128, 0, stream>>>(bufA, Wx0, bufB);
    // ---- layer 1 ----
    gemm_dual<<<GT, 512, 0, stream>>>(bufB, NP_, NP_, Wres1, bres1, bufA,
                                      Wn1, nullptr, hbuf, ra1, esrc, edst);
    edgep_kernel<<<EB, 256, 0, stream>>>(src, dst, posmap, esrc, edst, (float4*)pbuf);
    aggregate<<<dim3(N_, R_), 128, 0, stream>>>(hbuf, pbuf, rowptr, csr, resw1, bufA);
    cross_kernel<<<N_, 128, 0, stream>>>(bufA, Wx1, bufB);
    // ---- relation fusing ----
    fuse_kernel<<<N_, 128, 0, stream>>>(bufB, Wnf, rpb, (float*)d_out);
}

// Round 13
// 563.222 us; speedup vs baseline: 1.2668x; 1.1708x over previous
//
#include <hip/hip_runtime.h>
#include <hip/hip_bf16.h>

#define R_ 3
#define N_ 20000
#define NP_ 20096          // padded rows per relation (157 * 128)
#define E_ 250000
#define H_ 4
#define D_ 32
#define IN_ 128
#define NEG_ 0.2f

static __device__ __forceinline__ float leaky(float v) { return v >= 0.f ? v : NEG_ * v; }

static __device__ __forceinline__ float red32(float v) {
    #pragma unroll
    for (int m = 16; m > 0; m >>= 1) v += __shfl_xor(v, m, 64);
    return v;
}

// ---------------- CSR build ----------------
__global__ void count_kernel(const int* __restrict__ dst, int* __restrict__ cnt) {
    int i = blockIdx.x * blockDim.x + threadIdx.x;
    if (i < R_ * E_) {
        int r = i / E_;
        atomicAdd(&cnt[r * N_ + dst[i]], 1);
    }
}

__global__ __launch_bounds__(1024)
void scan_kernel(const int* __restrict__ cnt, int* __restrict__ rowptr, int* __restrict__ cursor) {
    const int r = blockIdx.x;
    const int t = threadIdx.x;
    const int CH = 20;               // 1024*20 >= 20000
    int local[CH];
    int s = 0;
    int b0 = t * CH;
    #pragma unroll
    for (int i = 0; i < CH; i++) {
        int idx = b0 + i;
        int v = (idx < N_) ? cnt[r * N_ + idx] : 0;
        local[i] = s;                // exclusive within thread
        s += v;
    }
    __shared__ int ts[1024];
    ts[t] = s;
    __syncthreads();
    for (int off = 1; off < 1024; off <<= 1) {
        int v = (t >= off) ? ts[t - off] : 0;
        __syncthreads();
        ts[t] += v;
        __syncthreads();
    }
    int texcl = ts[t] - s;
    #pragma unroll
    for (int i = 0; i < CH; i++) {
        int idx = b0 + i;
        if (idx < N_) {
            int p = texcl + local[i];
            rowptr[r * (N_ + 1) + idx] = p;
            cursor[r * N_ + idx] = p;
        }
    }
    if (t == 1023) rowptr[r * (N_ + 1) + N_] = ts[1023];
}

__global__ void fill_kernel(const int* __restrict__ src, const int* __restrict__ dst,
                            int* __restrict__ cursor, int* __restrict__ csr) {
    int i = blockIdx.x * blockDim.x + threadIdx.x;
    if (i < R_ * E_) {
        int r = i / E_;
        int d = dst[i];
        int pos = atomicAdd(&cursor[r * N_ + d], 1);   // relation-local slot
        csr[r * E_ + pos] = src[i];
    }
}

// ---------------- merged relation-embedding stage: ra + prop in one launch ----------------
// grid (R_, 2): y==0 -> ra[r][c] = sum_i re[r][i]*Wr[r][i][c] (256 cols)
//               y==1 -> remb[r][o] = sum_i re[r][i]*Wp[r][i][o] + bp[r][o] (128 cols)
__global__ void relprep_kernel(const float* __restrict__ re, const float* __restrict__ Wr,
                               float* __restrict__ ra, const float* __restrict__ Wp,
                               const float* __restrict__ bp, float* __restrict__ remb,
                               int relin) {
    const int r = blockIdx.x;
    if (blockIdx.y == 0) {
        const int c = threadIdx.x;  // 256
        float a = 0.f;
        #pragma unroll 8
        for (int i = 0; i < relin; i++) a += re[r * relin + i] * Wr[(r * relin + i) * 256 + c];
        ra[r * 256 + c] = a;
    } else if (threadIdx.x < 128) {
        const int o = threadIdx.x;
        float a = bp[r * 128 + o];
        #pragma unroll 8
        for (int i = 0; i < relin; i++) a += re[r * relin + i] * Wp[(r * relin + i) * 128 + o];
        remb[r * 128 + o] = a;
    }
}

__global__ void rp_kernel(const float* __restrict__ re2, const float* __restrict__ Wrf,
                          float* __restrict__ rp) {
    int r = blockIdx.x, t = threadIdx.x, h = t >> 5, d = t & 31;
    float a = 0.f;
    #pragma unroll
    for (int c = 0; c < 32; c++)
        a += re2[r * 128 + h * 32 + c] * Wrf[(((r * H_ + h) * D_) + c) * D_ + d];
    rp[r * 128 + t] = a;
}

// ---------------- projection folding, one launch: grid (129, 2), 128 threads ----------------
// y selects target (0: Wres0/bres0, 1: Wn0/none). x<128: Wc row; x==128: bias row.
__global__ void combine_kernel(const float* __restrict__ P, const float* __restrict__ pb,
                               const float* __restrict__ W0, const float* __restrict__ b0,
                               const float* __restrict__ W1,
                               float* __restrict__ Wc0, float* __restrict__ bc0,
                               float* __restrict__ Wc1, float* __restrict__ bc1) {
    const float* W = blockIdx.y ? W1 : W0;
    const int j = threadIdx.x;
    if (blockIdx.x < 128) {
        const int i = blockIdx.x;
        float a = 0.f;
        #pragma unroll 8
        for (int k = 0; k < 128; k++) a += P[i * 128 + k] * W[k * 128 + j];
        (blockIdx.y ? Wc1 : Wc0)[i * 128 + j] = a;
    } else {
        float a = blockIdx.y ? 0.f : b0[j];
        #pragma unroll 8
        for (int k = 0; k < 128; k++) a += pb[k] * W[k * 128 + j];
        (blockIdx.y ? bc1 : bc0)[j] = a;
    }
}

// ---------------- fused dual GEMM: 128x256 tile (Wa | Wb), 512 threads ----------------
// Ya = X@Wa + ba (residual), Yb = X@Wb (+bb) (messages) + attention dots.
// Col-split ownership keeps Bs fragment reads bank-conflict-free (round 11: 4.58M -> 723K).
__global__ __launch_bounds__(512)
void gemm_dual(const float* __restrict__ X, int ldrows, int nrows,
               const float* __restrict__ Wa, const float* __restrict__ ba,
               float* __restrict__ Ya,
               const float* __restrict__ Wb, const float* __restrict__ bb,
               float* __restrict__ Yb,
               const float* __restrict__ ra, float* __restrict__ esrc,
               float* __restrict__ edst) {
    const int t  = threadIdx.x;
    const int tx = t & 31;            // 32 col quads
    const int ty = t >> 5;            // 16 row groups of 8
    const int r  = blockIdx.y;
    const int row0 = blockIdx.x * 128;

    const float* Xrel = X + (size_t)r * ldrows * 128;

    __shared__ float As[32][132];     // transposed, padded
    __shared__ float Bs[32][256];     // [k][col]: cols 0-127 Wa, 128-255 Wb

    float acc[8][8];
    #pragma unroll
    for (int i = 0; i < 8; i++)
        #pragma unroll
        for (int j = 0; j < 8; j++) acc[i][j] = 0.f;

    const int kq = t & 7;
    for (int kb = 0; kb < 128; kb += 32) {
        __syncthreads();
        // stage A: 128 rows x 32 k, transposed
        #pragma unroll
        for (int j = 0; j < 2; j++) {
            int rowl = (t >> 3) + 64 * j;
            int rowg = row0 + rowl;
            int rowc = rowg < nrows ? rowg : nrows - 1;
            float4 v = *(const float4*)&Xrel[(size_t)rowc * 128 + kb + kq * 4];
            As[kq * 4 + 0][rowl] = v.x;
            As[kq * 4 + 1][rowl] = v.y;
            As[kq * 4 + 2][rowl] = v.z;
            As[kq * 4 + 3][rowl] = v.w;
        }
        // stage B: 32 k x 256 cols (Wa | Wb), contiguous per-wave writes
        #pragma unroll
        for (int j = 0; j < 4; j++) {
            int fi = t + 512 * j;
            int kk = fi >> 6;
            int colq = fi & 63;
            float4 v = (colq < 32)
                ? *(const float4*)&Wa[(size_t)(kb + kk) * 128 + colq * 4]
                : *(const float4*)&Wb[(size_t)(kb + kk) * 128 + (colq - 32) * 4];
            *(float4*)&Bs[kk][colq * 4] = v;
        }
        __syncthreads();
        #pragma unroll 8
        for (int k = 0; k < 32; k++) {
            float a[8], b[8];
            *(float4*)&a[0] = *(const float4*)&As[k][ty * 8];
            *(float4*)&a[4] = *(const float4*)&As[k][ty * 8 + 4];
            *(float4*)&b[0] = *(const float4*)&Bs[k][tx * 4];         // Wa quad
            *(float4*)&b[4] = *(const float4*)&Bs[k][tx * 4 + 128];   // Wb quad
            #pragma unroll
            for (int i = 0; i < 8; i++)
                #pragma unroll
                for (int j = 0; j < 8; j++) acc[i][j] += a[i] * b[j];
        }
    }

    const int col0 = tx * 4;
    float baq[4], bbq[4];
    #pragma unroll
    for (int j = 0; j < 4; j++) {
        baq[j] = ba[col0 + j];
        bbq[j] = bb ? bb[col0 + j] : 0.f;
    }
    #pragma unroll
    for (int i = 0; i < 8; i++)
        #pragma unroll
        for (int j = 0; j < 4; j++) {
            acc[i][j]     += baq[j];
            acc[i][4 + j] += bbq[j];
        }

    float* Yar = Ya + (size_t)r * NP_ * 128;
    float* Ybr = Yb + (size_t)r * NP_ * 128;
    const int hh = tx >> 3;           // head of this col quad
    float rad[4], ras[4];
    #pragma unroll
    for (int j = 0; j < 4; j++) {
        int c = (tx & 7) * 4 + j;     // col within head
        rad[j] = ra[(r * H_ + hh) * 64 + c];
        ras[j] = ra[(r * H_ + hh) * 64 + 32 + c];
    }
    #pragma unroll
    for (int i = 0; i < 8; i++) {
        int row = row0 + ty * 8 + i;
        float4 oa = {acc[i][0], acc[i][1], acc[i][2], acc[i][3]};
        float4 ob = {acc[i][4], acc[i][5], acc[i][6], acc[i][7]};
        *(float4*)&Yar[(size_t)row * 128 + col0] = oa;
        *(float4*)&Ybr[(size_t)row * 128 + col0] = ob;
        float vd = 0.f, vs = 0.f;
        #pragma unroll
        for (int j = 0; j < 4; j++) { vd += acc[i][4 + j] * rad[j]; vs += acc[i][4 + j] * ras[j]; }
        vd += __shfl_xor(vd, 1); vd += __shfl_xor(vd, 2); vd += __shfl_xor(vd, 4);
        vs += __shfl_xor(vs, 1); vs += __shfl_xor(vs, 2); vs += __shfl_xor(vs, 4);
        if ((tx & 7) == 0) {
            edst[((size_t)r * NP_ + row) * 4 + hh] = vd;
            esrc[((size_t)r * NP_ + row) * 4 + hh] = vs;
        }
    }
}

// ---------------- aggregation with inline attention numerator ----------------
// For CSR edge j of node n: p = exp(leaky(esrc[s][h] + edst[n][h])) computed inline
// (edgep kernel + pbuf/posmap eliminated). Softmax shift-free: logits are O(0.1).
__global__ __launch_bounds__(128)
void aggregate(const float* __restrict__ hbuf, const float* __restrict__ esrc,
               const float* __restrict__ edst, const int* __restrict__ rowptr,
               const int* __restrict__ csr, const float* __restrict__ resw,
               float* __restrict__ io) {
    const int n = blockIdx.x, r = blockIdx.y;
    const int t = threadIdx.x;
    const int lane32 = t & 31;        // channel quad index
    const int slot = t >> 5;          // edge slot 0..3
    const int h = lane32 >> 3;        // head of this channel quad
    const int beg = rowptr[r * (N_ + 1) + n];
    const int end = rowptr[r * (N_ + 1) + n + 1];
    const float ed = edst[((size_t)r * NP_ + n) * 4 + h];

    float4 acc = {0.f, 0.f, 0.f, 0.f};
    float psum = 0.f;
    for (int j0 = beg; j0 < end; j0 += 4) {
        int j = j0 + slot;
        bool valid = j < end;
        int jc = valid ? j : beg;
        int s = csr[r * E_ + jc];
        float es = esrc[((size_t)r * NP_ + s) * 4 + h];
        float p = valid ? __expf(leaky(es + ed)) : 0.f;
        const float4 hv = *(const float4*)&hbuf[((size_t)r * NP_ + s) * 128 + lane32 * 4];
        acc.x += p * hv.x; acc.y += p * hv.y; acc.z += p * hv.z; acc.w += p * hv.w;
        psum += p;
    }

    __shared__ float4 sacc[4][32];
    __shared__ float spsum[4][32];
    sacc[slot][lane32] = acc;
    spsum[slot][lane32] = psum;
    __syncthreads();
    if (t < 32) {
        float4 a0 = sacc[0][t], a1 = sacc[1][t], a2 = sacc[2][t], a3 = sacc[3][t];
        float ps = spsum[0][t] + spsum[1][t] + spsum[2][t] + spsum[3][t];
        float inv = 1.f / (ps + 1e-16f);
        float alpha = 1.f / (1.f + __expf(-resw[0]));
        float4* iop = (float4*)&io[((size_t)r * NP_ + n) * 128 + t * 4];
        float4 res = *iop;
        float4 o;
        o.x = fmaxf((a0.x + a1.x + a2.x + a3.x) * inv, 0.f) * alpha + res.x * (1.f - alpha);
        o.y = fmaxf((a0.y + a1.y + a2.y + a3.y) * inv, 0.f) * alpha + res.y * (1.f - alpha);
        o.z = fmaxf((a0.z + a1.z + a2.z + a3.z) * inv, 0.f) * alpha + res.z * (1.f - alpha);
        o.w = fmaxf((a0.w + a1.w + a2.w + a3.w) * inv, 0.f) * alpha + res.w * (1.f - alpha);
        *iop = o;
    }
}

// ---------------- cross-relation attention ----------------
__global__ __launch_bounds__(128)
void cross_kernel(const float* __restrict__ fin, const float* __restrict__ Wx,
                  float* __restrict__ fout) {
    const int n = blockIdx.x, t = threadIdx.x;
    float f[3];
    #pragma unroll
    for (int r = 0; r < 3; r++) f[r] = fin[((size_t)r * NP_ + n) * 128 + t];
    #pragma unroll
    for (int k = 0; k < 3; k++) {
        float w = Wx[k * 128 + t];
        float s[3];
        #pragma unroll
        for (int r = 0; r < 3; r++) s[r] = leaky(red32(f[r] * w));
        float mx = fmaxf(s[0], fmaxf(s[1], s[2]));
        float a0 = __expf(s[0] - mx), a1 = __expf(s[1] - mx), a2 = __expf(s[2] - mx);
        float den = a0 + a1 + a2;
        fout[((size_t)k * NP_ + n) * 128 + t] = (f[0] * a0 + f[1] * a1 + f[2] * a2) / den;
    }
}

// ---------------- relation fusing ----------------
__global__ __launch_bounds__(128)
void fuse_kernel(const float* __restrict__ fin, const float* __restrict__ Wnf,
                 const float* __restrict__ rp, float* __restrict__ out) {
    const int n = blockIdx.x, t = threadIdx.x, h = t >> 5, e = t & 31;
    __shared__ float sf[3][128];
    #pragma unroll
    for (int r = 0; r < 3; r++) sf[r][t] = fin[((size_t)r * NP_ + n) * 128 + t];
    __syncthreads();
    float hf[3];
    #pragma unroll
    for (int r = 0; r < 3; r++) {
        float a = 0.f;
        #pragma unroll
        for (int d = 0; d < 32; d++)
            a += sf[r][h * 32 + d] * Wnf[(((r * H_ + h) * D_) + d) * D_ + e];
        hf[r] = a;
    }
    float s[3];
    #pragma unroll
    for (int r = 0; r < 3; r++) s[r] = leaky(red32(hf[r] * rp[(r * H_ + h) * D_ + e]));
    float mx = fmaxf(s[0], fmaxf(s[1], s[2]));
    float a0 = __expf(s[0] - mx), a1 = __expf(s[1] - mx), a2 = __expf(s[2] - mx);
    float den = a0 + a1 + a2;
    out[(size_t)n * 128 + t] = (hf[0] * a0 + hf[1] * a1 + hf[2] * a2) / den;
}

extern "C" void kernel_launch(void* const* d_in, const int* in_sizes, int n_in,
                              void* d_out, int out_size, void* d_ws, size_t ws_size,
                              hipStream_t stream) {
    const float* x        = (const float*)d_in[0];
    const int*   src      = (const int*)d_in[1];
    const int*   dst      = (const int*)d_in[2];
    const float* proj_W   = (const float*)d_in[3];
    const float* proj_b   = (const float*)d_in[4];
    const float* rel_emb0 = (const float*)d_in[5];
    const float* Wn0      = (const float*)d_in[6];
    const float* Wr0      = (const float*)d_in[7];
    const float* Wp0      = (const float*)d_in[8];
    const float* bp0      = (const float*)d_in[9];
    const float* Wres0    = (const float*)d_in[10];
    const float* bres0    = (const float*)d_in[11];
    const float* resw0    = (const float*)d_in[12];
    const float* Wx0      = (const float*)d_in[13];
    const float* Wn1      = (const float*)d_in[14];
    const float* Wr1      = (const float*)d_in[15];
    const float* Wp1      = (const float*)d_in[16];
    const float* bp1      = (const float*)d_in[17];
    const float* Wres1    = (const float*)d_in[18];
    const float* bres1    = (const float*)d_in[19];
    const float* resw1    = (const float*)d_in[20];
    const float* Wx1      = (const float*)d_in[21];
    const float* Wnf      = (const float*)d_in[22];
    const float* Wrf      = (const float*)d_in[23];

    char* ws = (char*)d_ws;
    size_t off = 0;
    auto alloc = [&](size_t bytes) { char* p = ws + off; off = (off + bytes + 255) & ~(size_t)255; return p; };
    const size_t BIG = (size_t)R_ * NP_ * 128 * sizeof(float);
    float* bufA  = (float*)alloc(BIG);   // residual (X@Wres+b) -> layer output
    float* bufB  = (float*)alloc(BIG);   // cross output / next-layer input
    float* hbuf  = (float*)alloc(BIG);   // messages (X@Wn)
    float* esrc  = (float*)alloc((size_t)R_ * NP_ * H_ * sizeof(float));
    float* edst  = (float*)alloc((size_t)R_ * NP_ * H_ * sizeof(float));
    int*   cnt   = (int*)alloc((size_t)R_ * N_ * sizeof(int));
    int*   cursor= (int*)alloc((size_t)R_ * N_ * sizeof(int));
    int*   rowptr= (int*)alloc((size_t)R_ * (N_ + 1) * sizeof(int));
    int*   csr   = (int*)alloc((size_t)R_ * E_ * sizeof(int));
    float* remb1 = (float*)alloc((size_t)R_ * 128 * sizeof(float));
    float* remb2 = (float*)alloc((size_t)R_ * 128 * sizeof(float));
    float* ra0   = (float*)alloc((size_t)R_ * 256 * sizeof(float));
    float* ra1   = (float*)alloc((size_t)R_ * 256 * sizeof(float));
    float* rpb   = (float*)alloc((size_t)R_ * 128 * sizeof(float));
    float* Wres0c= (float*)alloc(128 * 128 * sizeof(float));
    float* Wn0c  = (float*)alloc(128 * 128 * sizeof(float));
    float* bres0c= (float*)alloc(128 * sizeof(float));
    float* bn0c  = (float*)alloc(128 * sizeof(float));

    // ---- CSR build (shared by both layers) ----
    hipMemsetAsync(cnt, 0, (size_t)R_ * N_ * sizeof(int), stream);
    const int EB = (R_ * E_ + 255) / 256;
    count_kernel<<<EB, 256, 0, stream>>>(dst, cnt);
    scan_kernel<<<R_, 1024, 0, stream>>>(cnt, rowptr, cursor);
    fill_kernel<<<EB, 256, 0, stream>>>(src, dst, cursor, csr);

    // ---- relation-embedding chain (merged stages) ----
    relprep_kernel<<<dim3(R_, 2), 256, 0, stream>>>(rel_emb0, Wr0, ra0, Wp0, bp0, remb1, 64);
    relprep_kernel<<<dim3(R_, 2), 256, 0, stream>>>(remb1, Wr1, ra1, Wp1, bp1, remb2, 128);
    rp_kernel<<<R_, 128, 0, stream>>>(remb2, Wrf, rpb);

    // ---- fold projection into layer-0 weights (one launch) ----
    combine_kernel<<<dim3(129, 2), 128, 0, stream>>>(proj_W, proj_b, Wres0, bres0, Wn0,
                                                     Wres0c, bres0c, Wn0c, bn0c);

    const dim3 GT(NP_ / 128, R_);   // 157 x 3 tile blocks
    // ---- layer 0 (projection folded) ----
    gemm_dual<<<GT, 512, 0, stream>>>(x, N_, N_, Wres0c, bres0c, bufA,
                                      Wn0c, bn0c, hbuf, ra0, esrc, edst);
    aggregate<<<dim3(N_, R_), 128, 0, stream>>>(hbuf, esrc, edst, rowptr, csr, resw0, bufA);
    cross_kernel<<<N_, 128, 0, stream>>>(bufA, Wx0, bufB);
    // ---- layer 1 ----
    gemm_dual<<<GT, 512, 0, stream>>>(bufB, NP_, NP_, Wres1, bres1, bufA,
                                      Wn1, nullptr, hbuf, ra1, esrc, edst);
    aggregate<<<dim3(N_, R_), 128, 0, stream>>>(hbuf, esrc, edst, rowptr, csr, resw1, bufA);
    cross_kernel<<<N_, 128, 0, stream>>>(bufA, Wx1, bufB);
    // ---- relation fusing ----
    fuse_kernel<<<N_, 128, 0, stream>>>(bufB, Wnf, rpb, (float*)d_out);
}

// Round 14
// 556.246 us; speedup vs baseline: 1.2827x; 1.0125x over previous
//
#include <hip/hip_runtime.h>
#include <hip/hip_bf16.h>

#define R_ 3
#define N_ 20000
#define NP_ 20096          // padded rows per relation (157 * 128)
#define E_ 250000
#define H_ 4
#define D_ 32
#define IN_ 128
#define NEG_ 0.2f

static __device__ __forceinline__ float leaky(float v) { return v >= 0.f ? v : NEG_ * v; }

static __device__ __forceinline__ float red32(float v) {
    #pragma unroll
    for (int m = 16; m > 0; m >>= 1) v += __shfl_xor(v, m, 64);
    return v;
}

// bf16 via bit ops (RNE) — avoids hip_bf16 API variance
static __device__ __forceinline__ unsigned short f2bf(float f) {
    unsigned int u = __float_as_uint(f);
    unsigned int rounding = 0x7fffu + ((u >> 16) & 1u);
    return (unsigned short)((u + rounding) >> 16);
}
static __device__ __forceinline__ float bf2f(unsigned short b) {
    return __uint_as_float(((unsigned int)b) << 16);
}

// ---------------- CSR build ----------------
__global__ void count_kernel(const int* __restrict__ dst, int* __restrict__ cnt) {
    int i = blockIdx.x * blockDim.x + threadIdx.x;
    if (i < R_ * E_) {
        int r = i / E_;
        atomicAdd(&cnt[r * N_ + dst[i]], 1);
    }
}

__global__ __launch_bounds__(1024)
void scan_kernel(const int* __restrict__ cnt, int* __restrict__ rowptr, int* __restrict__ cursor) {
    const int r = blockIdx.x;
    const int t = threadIdx.x;
    const int CH = 20;               // 1024*20 >= 20000
    int local[CH];
    int s = 0;
    int b0 = t * CH;
    #pragma unroll
    for (int i = 0; i < CH; i++) {
        int idx = b0 + i;
        int v = (idx < N_) ? cnt[r * N_ + idx] : 0;
        local[i] = s;                // exclusive within thread
        s += v;
    }
    __shared__ int ts[1024];
    ts[t] = s;
    __syncthreads();
    for (int off = 1; off < 1024; off <<= 1) {
        int v = (t >= off) ? ts[t - off] : 0;
        __syncthreads();
        ts[t] += v;
        __syncthreads();
    }
    int texcl = ts[t] - s;
    #pragma unroll
    for (int i = 0; i < CH; i++) {
        int idx = b0 + i;
        if (idx < N_) {
            int p = texcl + local[i];
            rowptr[r * (N_ + 1) + idx] = p;
            cursor[r * N_ + idx] = p;
        }
    }
    if (t == 1023) rowptr[r * (N_ + 1) + N_] = ts[1023];
}

__global__ void fill_kernel(const int* __restrict__ src, const int* __restrict__ dst,
                            int* __restrict__ cursor, int* __restrict__ csr) {
    int i = blockIdx.x * blockDim.x + threadIdx.x;
    if (i < R_ * E_) {
        int r = i / E_;
        int d = dst[i];
        int pos = atomicAdd(&cursor[r * N_ + d], 1);   // relation-local slot
        csr[r * E_ + pos] = src[i];
    }
}

// ---------------- merged relation-embedding stage: ra + prop in one launch ----------------
__global__ void relprep_kernel(const float* __restrict__ re, const float* __restrict__ Wr,
                               float* __restrict__ ra, const float* __restrict__ Wp,
                               const float* __restrict__ bp, float* __restrict__ remb,
                               int relin) {
    const int r = blockIdx.x;
    if (blockIdx.y == 0) {
        const int c = threadIdx.x;  // 256
        float a = 0.f;
        #pragma unroll 8
        for (int i = 0; i < relin; i++) a += re[r * relin + i] * Wr[(r * relin + i) * 256 + c];
        ra[r * 256 + c] = a;
    } else if (threadIdx.x < 128) {
        const int o = threadIdx.x;
        float a = bp[r * 128 + o];
        #pragma unroll 8
        for (int i = 0; i < relin; i++) a += re[r * relin + i] * Wp[(r * relin + i) * 128 + o];
        remb[r * 128 + o] = a;
    }
}

__global__ void rp_kernel(const float* __restrict__ re2, const float* __restrict__ Wrf,
                          float* __restrict__ rp) {
    int r = blockIdx.x, t = threadIdx.x, h = t >> 5, d = t & 31;
    float a = 0.f;
    #pragma unroll
    for (int c = 0; c < 32; c++)
        a += re2[r * 128 + h * 32 + c] * Wrf[(((r * H_ + h) * D_) + c) * D_ + d];
    rp[r * 128 + t] = a;
}

// ---------------- projection folding, one launch: grid (129, 2), 128 threads ----------------
__global__ void combine_kernel(const float* __restrict__ P, const float* __restrict__ pb,
                               const float* __restrict__ W0, const float* __restrict__ b0,
                               const float* __restrict__ W1,
                               float* __restrict__ Wc0, float* __restrict__ bc0,
                               float* __restrict__ Wc1, float* __restrict__ bc1) {
    const float* W = blockIdx.y ? W1 : W0;
    const int j = threadIdx.x;
    if (blockIdx.x < 128) {
        const int i = blockIdx.x;
        float a = 0.f;
        #pragma unroll 8
        for (int k = 0; k < 128; k++) a += P[i * 128 + k] * W[k * 128 + j];
        (blockIdx.y ? Wc1 : Wc0)[i * 128 + j] = a;
    } else {
        float a = blockIdx.y ? 0.f : b0[j];
        #pragma unroll 8
        for (int k = 0; k < 128; k++) a += pb[k] * W[k * 128 + j];
        (blockIdx.y ? bc1 : bc0)[j] = a;
    }
}

// ---------------- fused dual GEMM: 64x256 tile (Wa | Wb), 256 threads ----------------
// 64-row tiles double the grid (471 -> 942 blocks) for occupancy (round-11 lesson:
// gemm_dual was grid/latency-bound at 1.84 blocks/CU, not conflict-bound).
// Ya = X@Wa + ba (residual, f32), Yb = X@Wb (+bb) (messages, bf16) + attention dots (f32).
__global__ __launch_bounds__(256)
void gemm_dual(const float* __restrict__ X, int ldrows, int nrows,
               const float* __restrict__ Wa, const float* __restrict__ ba,
               float* __restrict__ Ya,
               const float* __restrict__ Wb, const float* __restrict__ bb,
               unsigned short* __restrict__ Yb,
               const float* __restrict__ ra, float* __restrict__ esrc,
               float* __restrict__ edst) {
    const int t  = threadIdx.x;
    const int tx = t & 31;            // 32 col quads (4 Wa cols + 4 Wb cols each)
    const int ty = t >> 5;            // 8 row groups of 8
    const int r  = blockIdx.y;
    const int row0 = blockIdx.x * 64;

    const float* Xrel = X + (size_t)r * ldrows * 128;

    __shared__ float As[32][68];      // transposed, padded (64 rows + 4)
    __shared__ float Bs[32][256];     // [k][col]: cols 0-127 Wa, 128-255 Wb

    float acc[8][8];
    #pragma unroll
    for (int i = 0; i < 8; i++)
        #pragma unroll
        for (int j = 0; j < 8; j++) acc[i][j] = 0.f;

    const int kq = t & 7;
    for (int kb = 0; kb < 128; kb += 32) {
        __syncthreads();
        // stage A: 64 rows x 32 k, transposed
        #pragma unroll
        for (int j = 0; j < 2; j++) {
            int rowl = (t >> 3) + 32 * j;
            int rowg = row0 + rowl;
            int rowc = rowg < nrows ? rowg : nrows - 1;
            float4 v = *(const float4*)&Xrel[(size_t)rowc * 128 + kb + kq * 4];
            As[kq * 4 + 0][rowl] = v.x;
            As[kq * 4 + 1][rowl] = v.y;
            As[kq * 4 + 2][rowl] = v.z;
            As[kq * 4 + 3][rowl] = v.w;
        }
        // stage B: 32 k x 256 cols (Wa | Wb), contiguous per-wave writes
        #pragma unroll
        for (int j = 0; j < 8; j++) {
            int fi = t + 256 * j;
            int kk = fi >> 6;
            int colq = fi & 63;
            float4 v = (colq < 32)
                ? *(const float4*)&Wa[(size_t)(kb + kk) * 128 + colq * 4]
                : *(const float4*)&Wb[(size_t)(kb + kk) * 128 + (colq - 32) * 4];
            *(float4*)&Bs[kk][colq * 4] = v;
        }
        __syncthreads();
        #pragma unroll 8
        for (int k = 0; k < 32; k++) {
            float a[8], b[8];
            *(float4*)&a[0] = *(const float4*)&As[k][ty * 8];
            *(float4*)&a[4] = *(const float4*)&As[k][ty * 8 + 4];
            *(float4*)&b[0] = *(const float4*)&Bs[k][tx * 4];         // Wa quad
            *(float4*)&b[4] = *(const float4*)&Bs[k][tx * 4 + 128];   // Wb quad
            #pragma unroll
            for (int i = 0; i < 8; i++)
                #pragma unroll
                for (int j = 0; j < 8; j++) acc[i][j] += a[i] * b[j];
        }
    }

    const int col0 = tx * 4;
    float baq[4], bbq[4];
    #pragma unroll
    for (int j = 0; j < 4; j++) {
        baq[j] = ba[col0 + j];
        bbq[j] = bb ? bb[col0 + j] : 0.f;
    }
    #pragma unroll
    for (int i = 0; i < 8; i++)
        #pragma unroll
        for (int j = 0; j < 4; j++) {
            acc[i][j]     += baq[j];
            acc[i][4 + j] += bbq[j];
        }

    float*          Yar = Ya + (size_t)r * NP_ * 128;
    unsigned short* Ybr = Yb + (size_t)r * NP_ * 128;
    const int hh = tx >> 3;           // head of this col quad
    float rad[4], ras[4];
    #pragma unroll
    for (int j = 0; j < 4; j++) {
        int c = (tx & 7) * 4 + j;     // col within head
        rad[j] = ra[(r * H_ + hh) * 64 + c];
        ras[j] = ra[(r * H_ + hh) * 64 + 32 + c];
    }
    #pragma unroll
    for (int i = 0; i < 8; i++) {
        int row = row0 + ty * 8 + i;
        float4 oa = {acc[i][0], acc[i][1], acc[i][2], acc[i][3]};
        *(float4*)&Yar[(size_t)row * 128 + col0] = oa;
        ushort4 ob;
        ob.x = f2bf(acc[i][4]); ob.y = f2bf(acc[i][5]);
        ob.z = f2bf(acc[i][6]); ob.w = f2bf(acc[i][7]);
        *(ushort4*)&Ybr[(size_t)row * 128 + col0] = ob;
        float vd = 0.f, vs = 0.f;
        #pragma unroll
        for (int j = 0; j < 4; j++) { vd += acc[i][4 + j] * rad[j]; vs += acc[i][4 + j] * ras[j]; }
        vd += __shfl_xor(vd, 1); vd += __shfl_xor(vd, 2); vd += __shfl_xor(vd, 4);
        vs += __shfl_xor(vs, 1); vs += __shfl_xor(vs, 2); vs += __shfl_xor(vs, 4);
        if ((tx & 7) == 0) {
            edst[((size_t)r * NP_ + row) * 4 + hh] = vd;
            esrc[((size_t)r * NP_ + row) * 4 + hh] = vs;
        }
    }
}

// ---------------- aggregation with inline attention numerator, bf16 gather ----------------
__global__ __launch_bounds__(128)
void aggregate(const unsigned short* __restrict__ hbuf, const float* __restrict__ esrc,
               const float* __restrict__ edst, const int* __restrict__ rowptr,
               const int* __restrict__ csr, const float* __restrict__ resw,
               float* __restrict__ io) {
    const int n = blockIdx.x, r = blockIdx.y;
    const int t = threadIdx.x;
    const int lane32 = t & 31;        // channel quad index
    const int slot = t >> 5;          // edge slot 0..3
    const int h = lane32 >> 3;        // head of this channel quad
    const int beg = rowptr[r * (N_ + 1) + n];
    const int end = rowptr[r * (N_ + 1) + n + 1];
    const float ed = edst[((size_t)r * NP_ + n) * 4 + h];

    float4 acc = {0.f, 0.f, 0.f, 0.f};
    float psum = 0.f;
    for (int j0 = beg; j0 < end; j0 += 4) {
        int j = j0 + slot;
        bool valid = j < end;
        int jc = valid ? j : beg;
        int s = csr[r * E_ + jc];
        float es = esrc[((size_t)r * NP_ + s) * 4 + h];
        float p = valid ? __expf(leaky(es + ed)) : 0.f;
        ushort4 hv = *(const ushort4*)&hbuf[((size_t)r * NP_ + s) * 128 + lane32 * 4];
        acc.x += p * bf2f(hv.x); acc.y += p * bf2f(hv.y);
        acc.z += p * bf2f(hv.z); acc.w += p * bf2f(hv.w);
        psum += p;
    }

    __shared__ float4 sacc[4][32];
    __shared__ float spsum[4][32];
    sacc[slot][lane32] = acc;
    spsum[slot][lane32] = psum;
    __syncthreads();
    if (t < 32) {
        float4 a0 = sacc[0][t], a1 = sacc[1][t], a2 = sacc[2][t], a3 = sacc[3][t];
        float ps = spsum[0][t] + spsum[1][t] + spsum[2][t] + spsum[3][t];
        float inv = 1.f / (ps + 1e-16f);
        float alpha = 1.f / (1.f + __expf(-resw[0]));
        float4* iop = (float4*)&io[((size_t)r * NP_ + n) * 128 + t * 4];
        float4 res = *iop;
        float4 o;
        o.x = fmaxf((a0.x + a1.x + a2.x + a3.x) * inv, 0.f) * alpha + res.x * (1.f - alpha);
        o.y = fmaxf((a0.y + a1.y + a2.y + a3.y) * inv, 0.f) * alpha + res.y * (1.f - alpha);
        o.z = fmaxf((a0.z + a1.z + a2.z + a3.z) * inv, 0.f) * alpha + res.z * (1.f - alpha);
        o.w = fmaxf((a0.w + a1.w + a2.w + a3.w) * inv, 0.f) * alpha + res.w * (1.f - alpha);
        *iop = o;
    }
}

// ---------------- cross-relation attention ----------------
__global__ __launch_bounds__(128)
void cross_kernel(const float* __restrict__ fin, const float* __restrict__ Wx,
                  float* __restrict__ fout) {
    const int n = blockIdx.x, t = threadIdx.x;
    float f[3];
    #pragma unroll
    for (int r = 0; r < 3; r++) f[r] = fin[((size_t)r * NP_ + n) * 128 + t];
    #pragma unroll
    for (int k = 0; k < 3; k++) {
        float w = Wx[k * 128 + t];
        float s[3];
        #pragma unroll
        for (int r = 0; r < 3; r++) s[r] = leaky(red32(f[r] * w));
        float mx = fmaxf(s[0], fmaxf(s[1], s[2]));
        float a0 = __expf(s[0] - mx), a1 = __expf(s[1] - mx), a2 = __expf(s[2] - mx);
        float den = a0 + a1 + a2;
        fout[((size_t)k * NP_ + n) * 128 + t] = (f[0] * a0 + f[1] * a1 + f[2] * a2) / den;
    }
}

// ---------------- relation fusing ----------------
__global__ __launch_bounds__(128)
void fuse_kernel(const float* __restrict__ fin, const float* __restrict__ Wnf,
                 const float* __restrict__ rp, float* __restrict__ out) {
    const int n = blockIdx.x, t = threadIdx.x, h = t >> 5, e = t & 31;
    __shared__ float sf[3][128];
    #pragma unroll
    for (int r = 0; r < 3; r++) sf[r][t] = fin[((size_t)r * NP_ + n) * 128 + t];
    __syncthreads();
    float hf[3];
    #pragma unroll
    for (int r = 0; r < 3; r++) {
        float a = 0.f;
        #pragma unroll
        for (int d = 0; d < 32; d++)
            a += sf[r][h * 32 + d] * Wnf[(((r * H_ + h) * D_) + d) * D_ + e];
        hf[r] = a;
    }
    float s[3];
    #pragma unroll
    for (int r = 0; r < 3; r++) s[r] = leaky(red32(hf[r] * rp[(r * H_ + h) * D_ + e]));
    float mx = fmaxf(s[0], fmaxf(s[1], s[2]));
    float a0 = __expf(s[0] - mx), a1 = __expf(s[1] - mx), a2 = __expf(s[2] - mx);
    float den = a0 + a1 + a2;
    out[(size_t)n * 128 + t] = (hf[0] * a0 + hf[1] * a1 + hf[2] * a2) / den;
}

extern "C" void kernel_launch(void* const* d_in, const int* in_sizes, int n_in,
                              void* d_out, int out_size, void* d_ws, size_t ws_size,
                              hipStream_t stream) {
    const float* x        = (const float*)d_in[0];
    const int*   src      = (const int*)d_in[1];
    const int*   dst      = (const int*)d_in[2];
    const float* proj_W   = (const float*)d_in[3];
    const float* proj_b   = (const float*)d_in[4];
    const float* rel_emb0 = (const float*)d_in[5];
    const float* Wn0      = (const float*)d_in[6];
    const float* Wr0      = (const float*)d_in[7];
    const float* Wp0      = (const float*)d_in[8];
    const float* bp0      = (const float*)d_in[9];
    const float* Wres0    = (const float*)d_in[10];
    const float* bres0    = (const float*)d_in[11];
    const float* resw0    = (const float*)d_in[12];
    const float* Wx0      = (const float*)d_in[13];
    const float* Wn1      = (const float*)d_in[14];
    const float* Wr1      = (const float*)d_in[15];
    const float* Wp1      = (const float*)d_in[16];
    const float* bp1      = (const float*)d_in[17];
    const float* Wres1    = (const float*)d_in[18];
    const float* bres1    = (const float*)d_in[19];
    const float* resw1    = (const float*)d_in[20];
    const float* Wx1      = (const float*)d_in[21];
    const float* Wnf      = (const float*)d_in[22];
    const float* Wrf      = (const float*)d_in[23];

    char* ws = (char*)d_ws;
    size_t off = 0;
    auto alloc = [&](size_t bytes) { char* p = ws + off; off = (off + bytes + 255) & ~(size_t)255; return p; };
    const size_t BIG = (size_t)R_ * NP_ * 128 * sizeof(float);
    float* bufA  = (float*)alloc(BIG);   // residual (X@Wres+b) -> layer output
    float* bufB  = (float*)alloc(BIG);   // cross output / next-layer input
    unsigned short* hbuf = (unsigned short*)alloc((size_t)R_ * NP_ * 128 * sizeof(unsigned short));
    float* esrc  = (float*)alloc((size_t)R_ * NP_ * H_ * sizeof(float));
    float* edst  = (float*)alloc((size_t)R_ * NP_ * H_ * sizeof(float));
    int*   cnt   = (int*)alloc((size_t)R_ * N_ * sizeof(int));
    int*   cursor= (int*)alloc((size_t)R_ * N_ * sizeof(int));
    int*   rowptr= (int*)alloc((size_t)R_ * (N_ + 1) * sizeof(int));
    int*   csr   = (int*)alloc((size_t)R_ * E_ * sizeof(int));
    float* remb1 = (float*)alloc((size_t)R_ * 128 * sizeof(float));
    float* remb2 = (float*)alloc((size_t)R_ * 128 * sizeof(float));
    float* ra0   = (float*)alloc((size_t)R_ * 256 * sizeof(float));
    float* ra1   = (float*)alloc((size_t)R_ * 256 * sizeof(float));
    float* rpb   = (float*)alloc((size_t)R_ * 128 * sizeof(float));
    float* Wres0c= (float*)alloc(128 * 128 * sizeof(float));
    float* Wn0c  = (float*)alloc(128 * 128 * sizeof(float));
    float* bres0c= (float*)alloc(128 * sizeof(float));
    float* bn0c  = (float*)alloc(128 * sizeof(float));

    // ---- CSR build (shared by both layers) ----
    hipMemsetAsync(cnt, 0, (size_t)R_ * N_ * sizeof(int), stream);
    const int EB = (R_ * E_ + 255) / 256;
    count_kernel<<<EB, 256, 0, stream>>>(dst, cnt);
    scan_kernel<<<R_, 1024, 0, stream>>>(cnt, rowptr, cursor);
    fill_kernel<<<EB, 256, 0, stream>>>(src, dst, cursor, csr);

    // ---- relation-embedding chain (merged stages) ----
    relprep_kernel<<<dim3(R_, 2), 256, 0, stream>>>(rel_emb0, Wr0, ra0, Wp0, bp0, remb1, 64);
    relprep_kernel<<<dim3(R_, 2), 256, 0, stream>>>(remb1, Wr1, ra1, Wp1, bp1, remb2, 128);
    rp_kernel<<<R_, 128, 0, stream>>>(remb2, Wrf, rpb);

    // ---- fold projection into layer-0 weights (one launch) ----
    combine_kernel<<<dim3(129, 2), 128, 0, stream>>>(proj_W, proj_b, Wres0, bres0, Wn0,
                                                     Wres0c, bres0c, Wn0c, bn0c);

    const dim3 GT(NP_ / 64, R_);   // 314 x 3 tile blocks (64-row tiles)
    // ---- layer 0 (projection folded) ----
    gemm_dual<<<GT, 256, 0, stream>>>(x, N_, N_, Wres0c, bres0c, bufA,
                                      Wn0c, bn0c, hbuf, ra0, esrc, edst);
    aggregate<<<dim3(N_, R_), 128, 0, stream>>>(hbuf, esrc, edst, rowptr, csr, resw0, bufA);
    cross_kernel<<<N_, 128, 0, stream>>>(bufA, Wx0, bufB);
    // ---- layer 1 ----
    gemm_dual<<<GT, 256, 0, stream>>>(bufB, NP_, NP_, Wres1, bres1, bufA,
                                      Wn1, nullptr, hbuf, ra1, esrc, edst);
    aggregate<<<dim3(N_, R_), 128, 0, stream>>>(hbuf, esrc, edst, rowptr, csr, resw1, bufA);
    cross_kernel<<<N_, 128, 0, stream>>>(bufA, Wx1, bufB);
    // ---- relation fusing ----
    fuse_kernel<<<N_, 128, 0, stream>>>(bufB, Wnf, rpb, (float*)d_out);
}